// Round 9
// baseline (590.753 us; speedup 1.0000x reference)
//
#include <hip/hip_runtime.h>
#include <math.h>

#define NN 50000
#define NE 800000
#define EBLOCKS4 (NE / 256)        // 3125 edge blocks (4 x 64-edge tiles)
#define WBLOCKS ((NN + 63) / 64)   // 782 world blocks

typedef float     f32x4  __attribute__((ext_vector_type(4)));
typedef __bf16    bf16x8 __attribute__((ext_vector_type(8)));
typedef _Float16  f16x2  __attribute__((ext_vector_type(2)));
typedef _Float16  f16x8  __attribute__((ext_vector_type(8)));

// ws layout: [0,256) m_agg_w (64 f32). [256,...) bf16 weight fragments.
#define WE1F_OFF 0        // 5120: We1||Wg1  (kc<5, ct<16)  K 136->160
#define WE2F_OFF 5120     // 1024: We2       (kc<4, ct<4)
#define WN1F_OFF 6144     // 2048: Wn1       (kc<4, ct<8)
#define WN2F_OFF 8192     // 1024: Wn2       (kc<4, ct<4)
#define WW1F_OFF 9216     // 1536: Ww1       (kc<3, ct<8)   K 67->96
#define WW2F_OFF 10752    // 1024: Ww2       (kc<4, ct<4)
#define NCHUNKS  11776

// d_out row n (256 B): first 128 B = f16[64] m_agg accumulator (atomic
// target, zeroed by prep); second 128 B = bf16[64] z_h row n (gather table,
// written by prep). node_kernel block n reads both halves of its rows then
// overwrites them -> race-free, zero extra workspace.

__device__ inline bf16x8 pack8(float4 a, float4 b) {
    bf16x8 r;
    r[0] = (__bf16)a.x; r[1] = (__bf16)a.y; r[2] = (__bf16)a.z; r[3] = (__bf16)a.w;
    r[4] = (__bf16)b.x; r[5] = (__bf16)b.y; r[6] = (__bf16)b.z; r[7] = (__bf16)b.w;
    return r;
}

// packed 2x f16 atomic fadd (global_atomic_pk_add_f16, gfx90a+).
__device__ inline void pk_atomic_add_f16(void* addr, f16x2 v) {
#if __has_builtin(__builtin_amdgcn_global_atomic_fadd_v2f16)
    __builtin_amdgcn_global_atomic_fadd_v2f16((f16x2*)addr, v);
#else
    asm volatile("global_atomic_pk_add_f16 %0, %1, off"
                 :: "v"(addr), "v"(v) : "memory");
#endif
}

// ------- single prep kernel: weight fragments + z-bf16 table + zeroing -----
__global__ __launch_bounds__(256) void prep(
    const float* __restrict__ We1, const float* __restrict__ Wg1,
    const float* __restrict__ We2, const float* __restrict__ Wn1,
    const float* __restrict__ Wn2, const float* __restrict__ Ww1,
    const float* __restrict__ Ww2, bf16x8* __restrict__ wsF,
    const float* __restrict__ z, float* __restrict__ db,
    float* __restrict__ m_agg_w)
{
    const int c = blockIdx.x * 256 + threadIdx.x;

    if (c < 64) m_agg_w[c] = 0.f;

    if (c < NN * 8) {      // z-table (2nd half) + zero f16 acc (1st half)
        int node = c >> 3, q = c & 7;
        const float4* s = (const float4*)(z + (long)node * 64) + q * 2;
        float4 a = s[0], b = s[1];
        *(bf16x8*)((char*)db + (long)node * 256 + 128 + q * 16) = pack8(a, b);
        float4 zz = {0.f, 0.f, 0.f, 0.f};
        *(float4*)((char*)db + (long)node * 256 + q * 16) = zz;
    }

    if (c >= NCHUNKS) return;
    const int lane = c & 63, l16 = lane & 15, row8 = ((lane >> 4) & 3) * 8;
    bf16x8 p;
    if (c < WE2F_OFF) {                       // We1 || Wg1, pad K 136->160
        int ct = (c >> 6) & 15, kc = c >> 10;
        int col = ct * 16 + l16;
        const float* src = (col < 128) ? (We1 + col) : (Wg1 + (col - 128));
#pragma unroll
        for (int i = 0; i < 8; i++) {
            int r = kc * 32 + row8 + i;
            p[i] = (__bf16)((r < 136) ? src[(size_t)r * 128] : 0.f);
        }
    } else if (c < WN1F_OFF) {
        int cc = c - WE2F_OFF; int ct = (cc >> 6) & 3, kc = cc >> 8;
        int col = ct * 16 + l16;
#pragma unroll
        for (int i = 0; i < 8; i++)
            p[i] = (__bf16)We2[(size_t)(kc * 32 + row8 + i) * 64 + col];
    } else if (c < WN2F_OFF) {
        int cc = c - WN1F_OFF; int ct = (cc >> 6) & 7, kc = cc >> 9;
        int col = ct * 16 + l16;
#pragma unroll
        for (int i = 0; i < 8; i++)
            p[i] = (__bf16)Wn1[(size_t)(kc * 32 + row8 + i) * 128 + col];
    } else if (c < WW1F_OFF) {
        int cc = c - WN2F_OFF; int ct = (cc >> 6) & 3, kc = cc >> 8;
        int col = ct * 16 + l16;
#pragma unroll
        for (int i = 0; i < 8; i++)
            p[i] = (__bf16)Wn2[(size_t)(kc * 32 + row8 + i) * 64 + col];
    } else if (c < WW2F_OFF) {                // Ww1, pad K 67->96
        int cc = c - WW1F_OFF; int ct = (cc >> 6) & 7, kc = cc >> 9;
        int col = ct * 16 + l16;
#pragma unroll
        for (int i = 0; i < 8; i++) {
            int r = kc * 32 + row8 + i;
            p[i] = (__bf16)((r < 67) ? Ww1[(size_t)r * 128 + col] : 0.f);
        }
    } else {
        int cc = c - WW2F_OFF; int ct = (cc >> 6) & 3, kc = cc >> 8;
        int col = ct * 16 + l16;
#pragma unroll
        for (int i = 0; i < 8; i++)
            p[i] = (__bf16)Ww2[(size_t)(kc * 32 + row8 + i) * 64 + col];
    }
    wsF[c] = p;
}

// --------- fused edge + world kernel ---------------------------------------
// Edge path (R9): 4 pipelined 64-edge tiles per block. ei prefetched 2 tiles
// ahead, z-rows 1 tile ahead (issued right after B1 -> latency covered by
// GEMM1, paid complete at B2's drain). Loop barrier B5 is a raw s_barrier
// (LDS hazard only) so scatter atomics stay in flight across tiles.
union FusedLds {
    bf16x8 XF[1280];                                   // edge XF 20 KB
    struct {
        bf16x8   HF[1024];                             // 16 KB
        _Float16 M[64 * 68];                           // 8.7 KB, stride 68
    } s;
};

__global__ __launch_bounds__(512, 6) void fused_kernel(
    const float* __restrict__ z_h, const int* __restrict__ ei,
    const bf16x8* __restrict__ We1F, const bf16x8* __restrict__ We2F,
    const float* __restrict__ be1, const float* __restrict__ be2,
    const float* __restrict__ bg1, const float* __restrict__ Wg2,
    const float* __restrict__ bg2,
    const float* __restrict__ pos_world,
    const bf16x8* __restrict__ Ww1F, const bf16x8* __restrict__ Ww2F,
    const float* __restrict__ bw1, const float* __restrict__ bw2,
    float* __restrict__ magg_rows,     // = d_out; acc first half, z-bf16 second
    float* __restrict__ m_agg_w)
{
    __shared__ FusedLds U;
    __shared__ int   tgt_s[64];
    __shared__ float gred[4][64];

    const int t = threadIdx.x;               // 0..511
    const int lane = t & 63, w = t >> 6;     // w 0..7
    const int quad = lane >> 4, l16 = lane & 15;

    if (blockIdx.x >= EBLOCKS4) {
        // ================= world path (64 nodes/block) ======================
        const int n0 = (blockIdx.x - EBLOCKS4) * 64;
        {   // gather
            int nn = t >> 3, q = t & 7;
            int mt = nn >> 4, l16e = nn & 15;
            int node = n0 + nn; if (node >= NN) node = NN - 1;
            if (q < 4) {
                const float4* zr = (const float4*)(z_h + (long)node * 64) + q * 4;
                float4 a0 = zr[0], a1 = zr[1], a2 = zr[2], a3 = zr[3];
                int kcs = q >> 1, qa = (q & 1) * 2;
                U.XF[(kcs * 4 + mt) * 64 + qa * 16 + l16e]       = pack8(a0, a1);
                U.XF[(kcs * 4 + mt) * 64 + (qa + 1) * 16 + l16e] = pack8(a2, a3);
            } else if (q == 4) {
                float4 a0 = *(const float4*)(z_h + (long)node * 64);
                bf16x8 f;
#pragma unroll
                for (int i = 0; i < 8; i++) f[i] = (__bf16)0.f;
                f[0] = (__bf16)(a0.x - pos_world[0]);
                f[1] = (__bf16)(a0.y - pos_world[1]);
                f[2] = (__bf16)(a0.z - pos_world[2]);
                U.XF[(8 + mt) * 64 + l16e] = f;
            } else {
                bf16x8 z;
#pragma unroll
                for (int i = 0; i < 8; i++) z[i] = (__bf16)0.f;
                U.XF[(8 + mt) * 64 + (q - 4) * 16 + l16e] = z;
            }
        }
        __syncthreads();

        f32x4 acc[4];
        {
            float b = bw1[w * 16 + l16];
#pragma unroll
            for (int mt = 0; mt < 4; mt++) { f32x4 v = {b, b, b, b}; acc[mt] = v; }
        }
#pragma unroll
        for (int kc = 0; kc < 3; kc++) {
            bf16x8 bfr = Ww1F[(kc * 8 + w) * 64 + lane];
#pragma unroll
            for (int mt = 0; mt < 4; mt++)
                acc[mt] = __builtin_amdgcn_mfma_f32_16x16x32_bf16(
                    U.XF[(kc * 4 + mt) * 64 + lane], bfr, acc[mt], 0, 0, 0);
        }
        __syncthreads();

        {   // relu + transpose -> HF
            __bf16* HFp = (__bf16*)U.s.HF;
            int cw = w * 16 + l16;
            int kc2 = cw >> 5, quad2 = (cw >> 3) & 3, ii = cw & 7;
#pragma unroll
            for (int mt = 0; mt < 4; mt++)
#pragma unroll
                for (int r = 0; r < 4; r++)
                    HFp[(((kc2 * 4 + mt) * 64) + quad2 * 16 + quad * 4 + r) * 8 + ii] =
                        (__bf16)fmaxf(acc[mt][r], 0.f);
        }
        __syncthreads();

        {   // GEMM2 + masked column-sum
            const int nt = w & 3, mh = w >> 2;
            f32x4 acc2[2];
            float b2 = bw2[nt * 16 + l16];
#pragma unroll
            for (int m = 0; m < 2; m++) { f32x4 v = {b2, b2, b2, b2}; acc2[m] = v; }
#pragma unroll
            for (int kc = 0; kc < 4; kc++) {
                bf16x8 b2f = Ww2F[(kc * 4 + nt) * 64 + lane];
#pragma unroll
                for (int m = 0; m < 2; m++)
                    acc2[m] = __builtin_amdgcn_mfma_f32_16x16x32_bf16(
                        U.s.HF[(kc * 4 + mh * 2 + m) * 64 + lane], b2f, acc2[m], 0, 0, 0);
            }
            float s = 0.f;
#pragma unroll
            for (int m = 0; m < 2; m++)
#pragma unroll
                for (int r = 0; r < 4; r++) {
                    int node = n0 + (mh * 2 + m) * 16 + quad * 4 + r;
                    s += (node < NN) ? acc2[m][r] : 0.f;
                }
            s += __shfl_xor(s, 16, 64);
            s += __shfl_xor(s, 32, 64);
            if (quad == 0) atomicAdd(m_agg_w + nt * 16 + l16, s);
        }
        return;
    }

    // ================= edge path: 4 pipelined 64-edge tiles =================
    const int ee = t >> 3, q = t & 7;
    const int emt = ee >> 4, l16e = ee & 15;
    const int eb0 = blockIdx.x * 256 + ee;   // this thread's edge in tile 0
    const int kcs = q >> 2, qslot = q & 3;

    int rs_c, rt_c, rs_n, rt_n, rs_n2 = 0, rt_n2 = 0;
    bf16x8 sa, ta, sa_n, ta_n;

    rs_c = ei[eb0];  rt_c = ei[NE + eb0];
    {
        const bf16x8* zs = (const bf16x8*)((const char*)magg_rows + (long)rs_c * 256 + 128);
        const bf16x8* zt = (const bf16x8*)((const char*)magg_rows + (long)rt_c * 256 + 128);
        sa = zs[q]; ta = zt[q];
    }
    rs_n = ei[eb0 + 64]; rt_n = ei[NE + eb0 + 64];

    for (int j = 0; j < 4; j++) {
        // ---- XF fill from registers ----
        U.XF[(kcs * 4 + emt) * 64 + qslot * 16 + l16e]       = sa;
        U.XF[((kcs + 2) * 4 + emt) * 64 + qslot * 16 + l16e] = ta;
        if (q == 4) tgt_s[ee] = rt_c;
        if (q == 0) {        // edge features (cols 128..135) from chunk 0
            float dx = (float)sa[0] - (float)ta[0];
            float dy = (float)sa[1] - (float)ta[1];
            float dz = (float)sa[2] - (float)ta[2];
            float ax = (float)sa[3], ay = (float)sa[4], az = (float)sa[5];
            float bx = (float)ta[3], by = (float)ta[4], bz = (float)ta[5];
            float cx = ay * bz - az * by;
            float cy = az * bx - ax * bz;
            float cz = ax * by - ay * bx;
            bf16x8 f;
            f[0] = (__bf16)dx; f[1] = (__bf16)dy; f[2] = (__bf16)dz;
            f[3] = (__bf16)(dx * dx + dy * dy + dz * dz);
            f[4] = (__bf16)cx; f[5] = (__bf16)cy; f[6] = (__bf16)cz;
            f[7] = (__bf16)sqrtf(cx * cx + cy * cy + cz * cz);
            U.XF[(16 + emt) * 64 + l16e] = f;
        } else if (q >= 5) { // zero pad (cols 136..159)
            bf16x8 z;
#pragma unroll
            for (int i = 0; i < 8; i++) z[i] = (__bf16)0.f;
            U.XF[(16 + emt) * 64 + (q - 4) * 16 + l16e] = z;
        }
        __syncthreads();                     // B1: XF + tgt_s ready

        // ---- prefetch: z rows for tile j+1, ei for tile j+2 ----
        // issued here so latency is covered by GEMM1; B2's drain pays them.
        if (j < 3) {
            const bf16x8* zs = (const bf16x8*)((const char*)magg_rows + (long)rs_n * 256 + 128);
            const bf16x8* zt = (const bf16x8*)((const char*)magg_rows + (long)rt_n * 256 + 128);
            sa_n = zs[q]; ta_n = zt[q];
        }
        if (j < 2) {
            rs_n2 = ei[eb0 + (j + 2) * 64];
            rt_n2 = ei[NE + eb0 + (j + 2) * 64];
        }

        // ---- GEMM1: wave owns 32 cols (tiles 2w, 2w+1), 1-ahead B prefetch --
        f32x4 acc[4][2];
#pragma unroll
        for (int nt = 0; nt < 2; nt++) {
            int col = (w * 2 + nt) * 16 + l16;
            float b = (col < 128) ? be1[col] : bg1[col - 128];
#pragma unroll
            for (int mt = 0; mt < 4; mt++) { f32x4 v = {b, b, b, b}; acc[mt][nt] = v; }
        }
        bf16x8 bcur0 = We1F[(w * 2) * 64 + lane];
        bf16x8 bcur1 = We1F[(w * 2 + 1) * 64 + lane];
#pragma unroll
        for (int kc = 0; kc < 5; kc++) {
            bf16x8 bnx0, bnx1;
            if (kc < 4) {
                bnx0 = We1F[((kc + 1) * 16 + w * 2) * 64 + lane];
                bnx1 = We1F[((kc + 1) * 16 + w * 2 + 1) * 64 + lane];
            }
#pragma unroll
            for (int mt = 0; mt < 4; mt++) {
                bf16x8 af = U.XF[(kc * 4 + mt) * 64 + lane];
                acc[mt][0] = __builtin_amdgcn_mfma_f32_16x16x32_bf16(af, bcur0, acc[mt][0], 0, 0, 0);
                acc[mt][1] = __builtin_amdgcn_mfma_f32_16x16x32_bf16(af, bcur1, acc[mt][1], 0, 0, 0);
            }
            bcur0 = bnx0; bcur1 = bnx1;
        }
        __syncthreads();                     // B2: XF reads done (HF may overwrite)

        if (w < 4) {
            // ---- message waves: relu + transpose into HF (GEMM2-A order) ----
            __bf16* HFp = (__bf16*)U.s.HF;
#pragma unroll
            for (int nt = 0; nt < 2; nt++) {
                int cw = (w * 2 + nt) * 16 + l16;
                int kc2 = cw >> 5, quad2 = (cw >> 3) & 3, ii = cw & 7;
#pragma unroll
                for (int mt = 0; mt < 4; mt++)
#pragma unroll
                    for (int r = 0; r < 4; r++)
                        HFp[(((kc2 * 4 + mt) * 64) + quad2 * 16 + quad * 4 + r) * 8 + ii] =
                            (__bf16)fmaxf(acc[mt][nt][r], 0.f);
            }
        } else {
            // ---- gate waves: in-register partials over their 32 gate cols ----
            float gp[4][4];
#pragma unroll
            for (int mt = 0; mt < 4; mt++)
#pragma unroll
                for (int r = 0; r < 4; r++) gp[mt][r] = 0.f;
#pragma unroll
            for (int nt = 0; nt < 2; nt++) {
                float wg = Wg2[((w - 4) * 2 + nt) * 16 + l16];
#pragma unroll
                for (int mt = 0; mt < 4; mt++)
#pragma unroll
                    for (int r = 0; r < 4; r++)
                        gp[mt][r] += fmaxf(acc[mt][nt][r], 0.f) * wg;
            }
#pragma unroll
            for (int mask = 1; mask < 16; mask <<= 1)
#pragma unroll
                for (int mt = 0; mt < 4; mt++)
#pragma unroll
                    for (int r = 0; r < 4; r++)
                        gp[mt][r] += __shfl_xor(gp[mt][r], mask, 64);
            if (l16 == 0) {
#pragma unroll
                for (int mt = 0; mt < 4; mt++)
#pragma unroll
                    for (int r = 0; r < 4; r++)
                        gred[(w - 4) & 3][mt * 16 + quad * 4 + r] = gp[mt][r];
            }
        }
        __syncthreads();                     // B3: HF + gred ready

        // ---- GEMM2 (waves 0-3) + redundant sigmoid + M pack ----
        if (w < 4) {
            f32x4 acc2[4];
            float b2 = be2[w * 16 + l16];
#pragma unroll
            for (int mt = 0; mt < 4; mt++) { f32x4 v = {b2, b2, b2, b2}; acc2[mt] = v; }
            bf16x8 c2 = We2F[w * 64 + lane];
#pragma unroll
            for (int kc = 0; kc < 4; kc++) {
                bf16x8 n2;
                if (kc < 3) n2 = We2F[((kc + 1) * 4 + w) * 64 + lane];
#pragma unroll
                for (int mt = 0; mt < 4; mt++)
                    acc2[mt] = __builtin_amdgcn_mfma_f32_16x16x32_bf16(
                        U.s.HF[(kc * 4 + mt) * 64 + lane], c2, acc2[mt], 0, 0, 0);
                c2 = n2;
            }

            float wgtreg;
            {
                float g = bg2[0] + gred[0][lane] + gred[1][lane]
                                 + gred[2][lane] + gred[3][lane];
                wgtreg = 1.f / (1.f + __expf(-g));
            }

#pragma unroll
            for (int mt = 0; mt < 4; mt++)
#pragma unroll
                for (int r = 0; r < 4; r++) {
                    int edge = mt * 16 + quad * 4 + r;
                    float wg = __shfl(wgtreg, edge, 64);
                    U.s.M[edge * 68 + w * 16 + l16] =
                        (_Float16)(acc2[mt][r] * wg);
                }
        }
        __syncthreads();                     // B4: M ready

        // ---- scatter: all 8 waves, packed v2f16 atomics ----
        {
            const int p = t & 31, eb = t >> 5;
            char* base = (char*)magg_rows;
#pragma unroll
            for (int k = 0; k < 4; k++) {
                int e = eb + k * 16;
                f16x2 v = *(const f16x2*)&U.s.M[e * 68 + p * 2];
                pk_atomic_add_f16(base + (long)tgt_s[e] * 256 + p * 4, v);
            }
        }

        if (j < 3) {
            // LDS-only hazard (M reads done per-thread before arrival):
            // raw s_barrier avoids __syncthreads' vmcnt(0) drain so the
            // scatter atomics stay in flight across tiles.
            asm volatile("s_barrier" ::: "memory");   // B5
            rs_c = rs_n; rt_c = rt_n;
            rs_n = rs_n2; rt_n = rt_n2;
            sa = sa_n; ta = ta_n;
        }
    }
}

// ---------------- node kernel: 512 thr, 2 barriers (separate XF/HF) --------
__global__ __launch_bounds__(512, 4) void node_kernel(
    const float* __restrict__ m_agg_w,
    const bf16x8* __restrict__ Wn1F, const bf16x8* __restrict__ Wn2F,
    const float* __restrict__ bn1, const float* __restrict__ bn2,
    float* __restrict__ outp)     // rows: f16 acc | bf16 z, then output
{
    __shared__ bf16x8 XF[1024];   // 16 KB
    __shared__ bf16x8 HF[1024];   // 16 KB (separate -> no XF/HF hazard barrier)
    const int t = threadIdx.x;
    const int n0 = blockIdx.x * 64;
    const int lane = t & 63, w = t >> 6;
    const int quad = lane >> 4, l16 = lane & 15;

    {   // gather: 8 threads/node; halves: z-bf16 | m_agg(f16) + m_agg_w
        int nn = t >> 3, q = t & 7;
        int mt = nn >> 4, l16e = nn & 15;
        int node = n0 + nn; if (node >= NN) node = NN - 1;
        int half = q >> 2, sub = q & 3;
        bf16x8 c0, c1;
        if (half == 0) {
            const bf16x8* zr = (const bf16x8*)((const char*)outp + (long)node * 256 + 128) + sub * 2;
            c0 = zr[0]; c1 = zr[1];
        } else {
            const f16x8* mr = (const f16x8*)((const char*)outp + (long)node * 256) + sub * 2;
            f16x8 r0 = mr[0], r1 = mr[1];
            const float* mw = m_agg_w + sub * 16;
#pragma unroll
            for (int i = 0; i < 8; i++) {
                c0[i] = (__bf16)((float)r0[i] + mw[i]);
                c1[i] = (__bf16)((float)r1[i] + mw[i + 8]);
            }
        }
        int kcs = (sub >> 1) + half * 2, qa = (sub & 1) * 2;
        XF[(kcs * 4 + mt) * 64 + qa * 16 + l16e]       = c0;
        XF[(kcs * 4 + mt) * 64 + (qa + 1) * 16 + l16e] = c1;
    }
    __syncthreads();                         // B1: XF ready

    f32x4 acc[4];
    {
        float b = bn1[w * 16 + l16];
#pragma unroll
        for (int mt = 0; mt < 4; mt++) { f32x4 v = {b, b, b, b}; acc[mt] = v; }
    }
#pragma unroll
    for (int kc = 0; kc < 4; kc++) {
        bf16x8 bfr = Wn1F[(kc * 8 + w) * 64 + lane];
#pragma unroll
        for (int mt = 0; mt < 4; mt++)
            acc[mt] = __builtin_amdgcn_mfma_f32_16x16x32_bf16(
                XF[(kc * 4 + mt) * 64 + lane], bfr, acc[mt], 0, 0, 0);
    }

    {   // relu + transpose -> HF (separate buffer: no barrier needed)
        __bf16* HFp = (__bf16*)HF;
        int cw = w * 16 + l16;
        int kc2 = cw >> 5, quad2 = (cw >> 3) & 3, ii = cw & 7;
#pragma unroll
        for (int mt = 0; mt < 4; mt++)
#pragma unroll
            for (int r = 0; r < 4; r++)
                HFp[(((kc2 * 4 + mt) * 64) + quad2 * 16 + quad * 4 + r) * 8 + ii] =
                    (__bf16)fmaxf(acc[mt][r], 0.f);
    }
    __syncthreads();                         // B2: HF ready

    {   // GEMM2 + store: nt = w&3, m-half mh = w>>2
        const int nt = w & 3, mh = w >> 2;
        f32x4 acc2[2];
        float b2 = bn2[nt * 16 + l16];
#pragma unroll
        for (int m = 0; m < 2; m++) { f32x4 v = {b2, b2, b2, b2}; acc2[m] = v; }
#pragma unroll
        for (int kc = 0; kc < 4; kc++) {
            bf16x8 b2f = Wn2F[(kc * 4 + nt) * 64 + lane];
#pragma unroll
            for (int m = 0; m < 2; m++)
                acc2[m] = __builtin_amdgcn_mfma_f32_16x16x32_bf16(
                    HF[(kc * 4 + mh * 2 + m) * 64 + lane], b2f, acc2[m], 0, 0, 0);
        }
#pragma unroll
        for (int m = 0; m < 2; m++)
#pragma unroll
            for (int r = 0; r < 4; r++) {
                int node = n0 + (mh * 2 + m) * 16 + quad * 4 + r;
                if (node < NN)
                    outp[(long)node * 64 + nt * 16 + l16] = acc2[m][r];
            }
    }
}

extern "C" void kernel_launch(void* const* d_in, const int* in_sizes, int n_in,
                              void* d_out, int out_size, void* d_ws, size_t ws_size,
                              hipStream_t stream)
{
    const float* z_h       = (const float*)d_in[0];
    const float* pos_world = (const float*)d_in[1];
    const int*   ei        = (const int*)d_in[2];
    const float* We1 = (const float*)d_in[3];  const float* be1 = (const float*)d_in[4];
    const float* We2 = (const float*)d_in[5];  const float* be2 = (const float*)d_in[6];
    const float* Wg1 = (const float*)d_in[7];  const float* bg1 = (const float*)d_in[8];
    const float* Wg2 = (const float*)d_in[9];  const float* bg2 = (const float*)d_in[10];
    const float* Wn1 = (const float*)d_in[11]; const float* bn1 = (const float*)d_in[12];
    const float* Wn2 = (const float*)d_in[13]; const float* bn2 = (const float*)d_in[14];
    const float* Ww1 = (const float*)d_in[15]; const float* bw1 = (const float*)d_in[16];
    const float* Ww2 = (const float*)d_in[17]; const float* bw2 = (const float*)d_in[18];

    float*  outp    = (float*)d_out;
    float*  m_agg_w = (float*)d_ws;         // 64 floats
    bf16x8* wsF     = (bf16x8*)((char*)d_ws + 256);

    prep<<<(NN * 8 + 255) / 256, 256, 0, stream>>>(
        We1, Wg1, We2, Wn1, Wn2, Ww1, Ww2, wsF, z_h, outp, m_agg_w);
    fused_kernel<<<EBLOCKS4 + WBLOCKS, 512, 0, stream>>>(
        z_h, ei, wsF + WE1F_OFF, wsF + WE2F_OFF,
        be1, be2, bg1, Wg2, bg2,
        pos_world, wsF + WW1F_OFF, wsF + WW2F_OFF, bw1, bw2,
        outp, m_agg_w);
    node_kernel<<<(NN + 63) / 64, 512, 0, stream>>>(
        m_agg_w, wsF + WN1F_OFF, wsF + WN2F_OFF, bn1, bn2, outp);
}

// Round 10
// 339.482 us; speedup vs baseline: 1.7402x; 1.7402x over previous
//
#include <hip/hip_runtime.h>
#include <math.h>

#define NN 50000
#define NE 800000
#define EBLOCKS4 (NE / 256)        // 3125 edge blocks (4 x 64-edge tiles)
#define WBLOCKS ((NN + 63) / 64)   // 782 world blocks

typedef float     f32x4  __attribute__((ext_vector_type(4)));
typedef __bf16    bf16x8 __attribute__((ext_vector_type(8)));
typedef _Float16  f16x2  __attribute__((ext_vector_type(2)));
typedef _Float16  f16x8  __attribute__((ext_vector_type(8)));

// lgkmcnt-only barrier: in-loop hazards are LDS-only; avoids __syncthreads'
// vmcnt(0) drain so global prefetches + scatter atomics stay in flight.
#define LBAR() do { \
    asm volatile("s_waitcnt lgkmcnt(0)" ::: "memory"); \
    __builtin_amdgcn_s_barrier(); \
} while (0)

// ws layout: [0,256) m_agg_w (64 f32). [256,...) bf16 weight fragments.
#define WE1F_OFF 0        // 5120: We1||Wg1  (kc<5, ct<16)  K 136->160
#define WE2F_OFF 5120     // 1024: We2       (kc<4, ct<4)
#define WN1F_OFF 6144     // 2048: Wn1       (kc<4, ct<8)
#define WN2F_OFF 8192     // 1024: Wn2       (kc<4, ct<4)
#define WW1F_OFF 9216     // 1536: Ww1       (kc<3, ct<8)   K 67->96
#define WW2F_OFF 10752    // 1024: Ww2       (kc<4, ct<4)
#define NCHUNKS  11776

// d_out row n (256 B): first 128 B = f16[64] m_agg accumulator (atomic
// target, zeroed by prep); second 128 B = bf16[64] z_h row n (gather table,
// written by prep). node_kernel block n reads both halves of its rows then
// overwrites them -> race-free, zero extra workspace.

__device__ inline bf16x8 pack8(float4 a, float4 b) {
    bf16x8 r;
    r[0] = (__bf16)a.x; r[1] = (__bf16)a.y; r[2] = (__bf16)a.z; r[3] = (__bf16)a.w;
    r[4] = (__bf16)b.x; r[5] = (__bf16)b.y; r[6] = (__bf16)b.z; r[7] = (__bf16)b.w;
    return r;
}

// packed 2x f16 atomic fadd (global_atomic_pk_add_f16, gfx90a+).
__device__ inline void pk_atomic_add_f16(void* addr, f16x2 v) {
#if __has_builtin(__builtin_amdgcn_global_atomic_fadd_v2f16)
    __builtin_amdgcn_global_atomic_fadd_v2f16((f16x2*)addr, v);
#else
    asm volatile("global_atomic_pk_add_f16 %0, %1, off"
                 :: "v"(addr), "v"(v) : "memory");
#endif
}

// ------- single prep kernel: weight fragments + z-bf16 table + zeroing -----
__global__ __launch_bounds__(256) void prep(
    const float* __restrict__ We1, const float* __restrict__ Wg1,
    const float* __restrict__ We2, const float* __restrict__ Wn1,
    const float* __restrict__ Wn2, const float* __restrict__ Ww1,
    const float* __restrict__ Ww2, bf16x8* __restrict__ wsF,
    const float* __restrict__ z, float* __restrict__ db,
    float* __restrict__ m_agg_w)
{
    const int c = blockIdx.x * 256 + threadIdx.x;

    if (c < 64) m_agg_w[c] = 0.f;

    if (c < NN * 8) {      // z-table (2nd half) + zero f16 acc (1st half)
        int node = c >> 3, q = c & 7;
        const float4* s = (const float4*)(z + (long)node * 64) + q * 2;
        float4 a = s[0], b = s[1];
        *(bf16x8*)((char*)db + (long)node * 256 + 128 + q * 16) = pack8(a, b);
        float4 zz = {0.f, 0.f, 0.f, 0.f};
        *(float4*)((char*)db + (long)node * 256 + q * 16) = zz;
    }

    if (c >= NCHUNKS) return;
    const int lane = c & 63, l16 = lane & 15, row8 = ((lane >> 4) & 3) * 8;
    bf16x8 p;
    if (c < WE2F_OFF) {                       // We1 || Wg1, pad K 136->160
        int ct = (c >> 6) & 15, kc = c >> 10;
        int col = ct * 16 + l16;
        const float* src = (col < 128) ? (We1 + col) : (Wg1 + (col - 128));
#pragma unroll
        for (int i = 0; i < 8; i++) {
            int r = kc * 32 + row8 + i;
            p[i] = (__bf16)((r < 136) ? src[(size_t)r * 128] : 0.f);
        }
    } else if (c < WN1F_OFF) {
        int cc = c - WE2F_OFF; int ct = (cc >> 6) & 3, kc = cc >> 8;
        int col = ct * 16 + l16;
#pragma unroll
        for (int i = 0; i < 8; i++)
            p[i] = (__bf16)We2[(size_t)(kc * 32 + row8 + i) * 64 + col];
    } else if (c < WN2F_OFF) {
        int cc = c - WN1F_OFF; int ct = (cc >> 6) & 7, kc = cc >> 9;
        int col = ct * 16 + l16;
#pragma unroll
        for (int i = 0; i < 8; i++)
            p[i] = (__bf16)Wn1[(size_t)(kc * 32 + row8 + i) * 128 + col];
    } else if (c < WW1F_OFF) {
        int cc = c - WN2F_OFF; int ct = (cc >> 6) & 3, kc = cc >> 8;
        int col = ct * 16 + l16;
#pragma unroll
        for (int i = 0; i < 8; i++)
            p[i] = (__bf16)Wn2[(size_t)(kc * 32 + row8 + i) * 64 + col];
    } else if (c < WW2F_OFF) {                // Ww1, pad K 67->96
        int cc = c - WW1F_OFF; int ct = (cc >> 6) & 7, kc = cc >> 9;
        int col = ct * 16 + l16;
#pragma unroll
        for (int i = 0; i < 8; i++) {
            int r = kc * 32 + row8 + i;
            p[i] = (__bf16)((r < 67) ? Ww1[(size_t)r * 128 + col] : 0.f);
        }
    } else {
        int cc = c - WW2F_OFF; int ct = (cc >> 6) & 3, kc = cc >> 8;
        int col = ct * 16 + l16;
#pragma unroll
        for (int i = 0; i < 8; i++)
            p[i] = (__bf16)Ww2[(size_t)(kc * 32 + row8 + i) * 64 + col];
    }
    wsF[c] = p;
}

// --------- fused edge + world kernel ---------------------------------------
// Edge path (R10 = R9 fixed): 4 pipelined 64-edge tiles per block. ei
// prefetched 2 tiles ahead, z-rows 1 tile ahead. launch_bounds(512,4) gives
// the allocator 128 VGPRs so the prefetch registers DON'T spill (R9's 2 GB
// scratch bug). All in-loop barriers are lgkmcnt-only so prefetches and
// scatter atomics stay in flight across tiles (no vmcnt(0) drains).
union FusedLds {
    bf16x8 XF[1280];                                   // edge XF 20 KB
    struct {
        bf16x8   HF[1024];                             // 16 KB
        _Float16 M[64 * 68];                           // 8.7 KB, stride 68
    } s;
};

__global__ __launch_bounds__(512, 4) void fused_kernel(
    const float* __restrict__ z_h, const int* __restrict__ ei,
    const bf16x8* __restrict__ We1F, const bf16x8* __restrict__ We2F,
    const float* __restrict__ be1, const float* __restrict__ be2,
    const float* __restrict__ bg1, const float* __restrict__ Wg2,
    const float* __restrict__ bg2,
    const float* __restrict__ pos_world,
    const bf16x8* __restrict__ Ww1F, const bf16x8* __restrict__ Ww2F,
    const float* __restrict__ bw1, const float* __restrict__ bw2,
    float* __restrict__ magg_rows,     // = d_out; acc first half, z-bf16 second
    float* __restrict__ m_agg_w)
{
    __shared__ FusedLds U;
    __shared__ int   tgt_s[64];
    __shared__ float gred[4][64];

    const int t = threadIdx.x;               // 0..511
    const int lane = t & 63, w = t >> 6;     // w 0..7
    const int quad = lane >> 4, l16 = lane & 15;

    if (blockIdx.x >= EBLOCKS4) {
        // ================= world path (64 nodes/block) ======================
        const int n0 = (blockIdx.x - EBLOCKS4) * 64;
        {   // gather
            int nn = t >> 3, q = t & 7;
            int mt = nn >> 4, l16e = nn & 15;
            int node = n0 + nn; if (node >= NN) node = NN - 1;
            if (q < 4) {
                const float4* zr = (const float4*)(z_h + (long)node * 64) + q * 4;
                float4 a0 = zr[0], a1 = zr[1], a2 = zr[2], a3 = zr[3];
                int kcs = q >> 1, qa = (q & 1) * 2;
                U.XF[(kcs * 4 + mt) * 64 + qa * 16 + l16e]       = pack8(a0, a1);
                U.XF[(kcs * 4 + mt) * 64 + (qa + 1) * 16 + l16e] = pack8(a2, a3);
            } else if (q == 4) {
                float4 a0 = *(const float4*)(z_h + (long)node * 64);
                bf16x8 f;
#pragma unroll
                for (int i = 0; i < 8; i++) f[i] = (__bf16)0.f;
                f[0] = (__bf16)(a0.x - pos_world[0]);
                f[1] = (__bf16)(a0.y - pos_world[1]);
                f[2] = (__bf16)(a0.z - pos_world[2]);
                U.XF[(8 + mt) * 64 + l16e] = f;
            } else {
                bf16x8 z;
#pragma unroll
                for (int i = 0; i < 8; i++) z[i] = (__bf16)0.f;
                U.XF[(8 + mt) * 64 + (q - 4) * 16 + l16e] = z;
            }
        }
        __syncthreads();

        f32x4 acc[4];
        {
            float b = bw1[w * 16 + l16];
#pragma unroll
            for (int mt = 0; mt < 4; mt++) { f32x4 v = {b, b, b, b}; acc[mt] = v; }
        }
#pragma unroll
        for (int kc = 0; kc < 3; kc++) {
            bf16x8 bfr = Ww1F[(kc * 8 + w) * 64 + lane];
#pragma unroll
            for (int mt = 0; mt < 4; mt++)
                acc[mt] = __builtin_amdgcn_mfma_f32_16x16x32_bf16(
                    U.XF[(kc * 4 + mt) * 64 + lane], bfr, acc[mt], 0, 0, 0);
        }
        __syncthreads();

        {   // relu + transpose -> HF
            __bf16* HFp = (__bf16*)U.s.HF;
            int cw = w * 16 + l16;
            int kc2 = cw >> 5, quad2 = (cw >> 3) & 3, ii = cw & 7;
#pragma unroll
            for (int mt = 0; mt < 4; mt++)
#pragma unroll
                for (int r = 0; r < 4; r++)
                    HFp[(((kc2 * 4 + mt) * 64) + quad2 * 16 + quad * 4 + r) * 8 + ii] =
                        (__bf16)fmaxf(acc[mt][r], 0.f);
        }
        __syncthreads();

        {   // GEMM2 + masked column-sum
            const int nt = w & 3, mh = w >> 2;
            f32x4 acc2[2];
            float b2 = bw2[nt * 16 + l16];
#pragma unroll
            for (int m = 0; m < 2; m++) { f32x4 v = {b2, b2, b2, b2}; acc2[m] = v; }
#pragma unroll
            for (int kc = 0; kc < 4; kc++) {
                bf16x8 b2f = Ww2F[(kc * 4 + nt) * 64 + lane];
#pragma unroll
                for (int m = 0; m < 2; m++)
                    acc2[m] = __builtin_amdgcn_mfma_f32_16x16x32_bf16(
                        U.s.HF[(kc * 4 + mh * 2 + m) * 64 + lane], b2f, acc2[m], 0, 0, 0);
            }
            float s = 0.f;
#pragma unroll
            for (int m = 0; m < 2; m++)
#pragma unroll
                for (int r = 0; r < 4; r++) {
                    int node = n0 + (mh * 2 + m) * 16 + quad * 4 + r;
                    s += (node < NN) ? acc2[m][r] : 0.f;
                }
            s += __shfl_xor(s, 16, 64);
            s += __shfl_xor(s, 32, 64);
            if (quad == 0) atomicAdd(m_agg_w + nt * 16 + l16, s);
        }
        return;
    }

    // ================= edge path: 4 pipelined 64-edge tiles =================
    const int ee = t >> 3, q = t & 7;
    const int emt = ee >> 4, l16e = ee & 15;
    const int eb0 = blockIdx.x * 256 + ee;   // this thread's edge in tile 0
    const int kcs = q >> 2, qslot = q & 3;

    int rs_c, rt_c, rs_n, rt_n, rs_n2 = 0, rt_n2 = 0;
    bf16x8 sa, ta, sa_n, ta_n;

    rs_c = ei[eb0];  rt_c = ei[NE + eb0];
    {
        const bf16x8* zs = (const bf16x8*)((const char*)magg_rows + (long)rs_c * 256 + 128);
        const bf16x8* zt = (const bf16x8*)((const char*)magg_rows + (long)rt_c * 256 + 128);
        sa = zs[q]; ta = zt[q];
    }
    rs_n = ei[eb0 + 64]; rt_n = ei[NE + eb0 + 64];

    for (int j = 0; j < 4; j++) {
        // ---- XF fill from registers ----
        U.XF[(kcs * 4 + emt) * 64 + qslot * 16 + l16e]       = sa;
        U.XF[((kcs + 2) * 4 + emt) * 64 + qslot * 16 + l16e] = ta;
        if (q == 4) tgt_s[ee] = rt_c;
        if (q == 0) {        // edge features (cols 128..135) from chunk 0
            float dx = (float)sa[0] - (float)ta[0];
            float dy = (float)sa[1] - (float)ta[1];
            float dz = (float)sa[2] - (float)ta[2];
            float ax = (float)sa[3], ay = (float)sa[4], az = (float)sa[5];
            float bx = (float)ta[3], by = (float)ta[4], bz = (float)ta[5];
            float cx = ay * bz - az * by;
            float cy = az * bx - ax * bz;
            float cz = ax * by - ay * bx;
            bf16x8 f;
            f[0] = (__bf16)dx; f[1] = (__bf16)dy; f[2] = (__bf16)dz;
            f[3] = (__bf16)(dx * dx + dy * dy + dz * dz);
            f[4] = (__bf16)cx; f[5] = (__bf16)cy; f[6] = (__bf16)cz;
            f[7] = (__bf16)sqrtf(cx * cx + cy * cy + cz * cz);
            U.XF[(16 + emt) * 64 + l16e] = f;
        } else if (q >= 5) { // zero pad (cols 136..159)
            bf16x8 z;
#pragma unroll
            for (int i = 0; i < 8; i++) z[i] = (__bf16)0.f;
            U.XF[(16 + emt) * 64 + (q - 4) * 16 + l16e] = z;
        }
        LBAR();                              // B1: XF + tgt_s ready (LDS only)

        // ---- prefetch: z rows for tile j+1, ei for tile j+2 ----
        // latency hidden under GEMM1/GEMM2; no barrier drains vmcnt.
        if (j < 3) {
            const bf16x8* zs = (const bf16x8*)((const char*)magg_rows + (long)rs_n * 256 + 128);
            const bf16x8* zt = (const bf16x8*)((const char*)magg_rows + (long)rt_n * 256 + 128);
            sa_n = zs[q]; ta_n = zt[q];
        }
        if (j < 2) {
            rs_n2 = ei[eb0 + (j + 2) * 64];
            rt_n2 = ei[NE + eb0 + (j + 2) * 64];
        }

        // ---- GEMM1: wave owns 32 cols (tiles 2w, 2w+1), 1-ahead B prefetch --
        f32x4 acc[4][2];
#pragma unroll
        for (int nt = 0; nt < 2; nt++) {
            int col = (w * 2 + nt) * 16 + l16;
            float b = (col < 128) ? be1[col] : bg1[col - 128];
#pragma unroll
            for (int mt = 0; mt < 4; mt++) { f32x4 v = {b, b, b, b}; acc[mt][nt] = v; }
        }
        bf16x8 bcur0 = We1F[(w * 2) * 64 + lane];
        bf16x8 bcur1 = We1F[(w * 2 + 1) * 64 + lane];
#pragma unroll
        for (int kc = 0; kc < 5; kc++) {
            bf16x8 bnx0, bnx1;
            if (kc < 4) {
                bnx0 = We1F[((kc + 1) * 16 + w * 2) * 64 + lane];
                bnx1 = We1F[((kc + 1) * 16 + w * 2 + 1) * 64 + lane];
            }
#pragma unroll
            for (int mt = 0; mt < 4; mt++) {
                bf16x8 af = U.XF[(kc * 4 + mt) * 64 + lane];
                acc[mt][0] = __builtin_amdgcn_mfma_f32_16x16x32_bf16(af, bcur0, acc[mt][0], 0, 0, 0);
                acc[mt][1] = __builtin_amdgcn_mfma_f32_16x16x32_bf16(af, bcur1, acc[mt][1], 0, 0, 0);
            }
            bcur0 = bnx0; bcur1 = bnx1;
        }
        LBAR();                              // B2: XF reads done (HF may overwrite)

        if (w < 4) {
            // ---- message waves: relu + transpose into HF (GEMM2-A order) ----
            __bf16* HFp = (__bf16*)U.s.HF;
#pragma unroll
            for (int nt = 0; nt < 2; nt++) {
                int cw = (w * 2 + nt) * 16 + l16;
                int kc2 = cw >> 5, quad2 = (cw >> 3) & 3, ii = cw & 7;
#pragma unroll
                for (int mt = 0; mt < 4; mt++)
#pragma unroll
                    for (int r = 0; r < 4; r++)
                        HFp[(((kc2 * 4 + mt) * 64) + quad2 * 16 + quad * 4 + r) * 8 + ii] =
                            (__bf16)fmaxf(acc[mt][nt][r], 0.f);
            }
        } else {
            // ---- gate waves: in-register partials over their 32 gate cols ----
            float gp[4][4];
#pragma unroll
            for (int mt = 0; mt < 4; mt++)
#pragma unroll
                for (int r = 0; r < 4; r++) gp[mt][r] = 0.f;
#pragma unroll
            for (int nt = 0; nt < 2; nt++) {
                float wg = Wg2[((w - 4) * 2 + nt) * 16 + l16];
#pragma unroll
                for (int mt = 0; mt < 4; mt++)
#pragma unroll
                    for (int r = 0; r < 4; r++)
                        gp[mt][r] += fmaxf(acc[mt][nt][r], 0.f) * wg;
            }
#pragma unroll
            for (int mask = 1; mask < 16; mask <<= 1)
#pragma unroll
                for (int mt = 0; mt < 4; mt++)
#pragma unroll
                    for (int r = 0; r < 4; r++)
                        gp[mt][r] += __shfl_xor(gp[mt][r], mask, 64);
            if (l16 == 0) {
#pragma unroll
                for (int mt = 0; mt < 4; mt++)
#pragma unroll
                    for (int r = 0; r < 4; r++)
                        gred[(w - 4) & 3][mt * 16 + quad * 4 + r] = gp[mt][r];
            }
        }
        LBAR();                              // B3: HF + gred ready

        // ---- GEMM2 (waves 0-3) + redundant sigmoid + M pack ----
        if (w < 4) {
            f32x4 acc2[4];
            float b2 = be2[w * 16 + l16];
#pragma unroll
            for (int mt = 0; mt < 4; mt++) { f32x4 v = {b2, b2, b2, b2}; acc2[mt] = v; }
            bf16x8 c2 = We2F[w * 64 + lane];
#pragma unroll
            for (int kc = 0; kc < 4; kc++) {
                bf16x8 n2;
                if (kc < 3) n2 = We2F[((kc + 1) * 4 + w) * 64 + lane];
#pragma unroll
                for (int mt = 0; mt < 4; mt++)
                    acc2[mt] = __builtin_amdgcn_mfma_f32_16x16x32_bf16(
                        U.s.HF[(kc * 4 + mt) * 64 + lane], c2, acc2[mt], 0, 0, 0);
                c2 = n2;
            }

            float wgtreg;
            {
                float g = bg2[0] + gred[0][lane] + gred[1][lane]
                                 + gred[2][lane] + gred[3][lane];
                wgtreg = 1.f / (1.f + __expf(-g));
            }

#pragma unroll
            for (int mt = 0; mt < 4; mt++)
#pragma unroll
                for (int r = 0; r < 4; r++) {
                    int edge = mt * 16 + quad * 4 + r;
                    float wg = __shfl(wgtreg, edge, 64);
                    U.s.M[edge * 68 + w * 16 + l16] =
                        (_Float16)(acc2[mt][r] * wg);
                }
        }
        LBAR();                              // B4: M ready

        // ---- scatter: all 8 waves, packed v2f16 atomics ----
        {
            const int p = t & 31, eb = t >> 5;
            char* base = (char*)magg_rows;
#pragma unroll
            for (int k = 0; k < 4; k++) {
                int e = eb + k * 16;
                f16x2 v = *(const f16x2*)&U.s.M[e * 68 + p * 2];
                pk_atomic_add_f16(base + (long)tgt_s[e] * 256 + p * 4, v);
            }
        }

        if (j < 3) {
            LBAR();                          // B5: M/tgt_s reads done before overwrite
            rs_c = rs_n; rt_c = rt_n;
            rs_n = rs_n2; rt_n = rt_n2;
            sa = sa_n; ta = ta_n;
        }
    }
}

// ---------------- node kernel: 512 thr, 2 barriers (separate XF/HF) --------
__global__ __launch_bounds__(512, 4) void node_kernel(
    const float* __restrict__ m_agg_w,
    const bf16x8* __restrict__ Wn1F, const bf16x8* __restrict__ Wn2F,
    const float* __restrict__ bn1, const float* __restrict__ bn2,
    float* __restrict__ outp)     // rows: f16 acc | bf16 z, then output
{
    __shared__ bf16x8 XF[1024];   // 16 KB
    __shared__ bf16x8 HF[1024];   // 16 KB (separate -> no XF/HF hazard barrier)
    const int t = threadIdx.x;
    const int n0 = blockIdx.x * 64;
    const int lane = t & 63, w = t >> 6;
    const int quad = lane >> 4, l16 = lane & 15;

    {   // gather: 8 threads/node; halves: z-bf16 | m_agg(f16) + m_agg_w
        int nn = t >> 3, q = t & 7;
        int mt = nn >> 4, l16e = nn & 15;
        int node = n0 + nn; if (node >= NN) node = NN - 1;
        int half = q >> 2, sub = q & 3;
        bf16x8 c0, c1;
        if (half == 0) {
            const bf16x8* zr = (const bf16x8*)((const char*)outp + (long)node * 256 + 128) + sub * 2;
            c0 = zr[0]; c1 = zr[1];
        } else {
            const f16x8* mr = (const f16x8*)((const char*)outp + (long)node * 256) + sub * 2;
            f16x8 r0 = mr[0], r1 = mr[1];
            const float* mw = m_agg_w + sub * 16;
#pragma unroll
            for (int i = 0; i < 8; i++) {
                c0[i] = (__bf16)((float)r0[i] + mw[i]);
                c1[i] = (__bf16)((float)r1[i] + mw[i + 8]);
            }
        }
        int kcs = (sub >> 1) + half * 2, qa = (sub & 1) * 2;
        XF[(kcs * 4 + mt) * 64 + qa * 16 + l16e]       = c0;
        XF[(kcs * 4 + mt) * 64 + (qa + 1) * 16 + l16e] = c1;
    }
    __syncthreads();                         // B1: XF ready

    f32x4 acc[4];
    {
        float b = bn1[w * 16 + l16];
#pragma unroll
        for (int mt = 0; mt < 4; mt++) { f32x4 v = {b, b, b, b}; acc[mt] = v; }
    }
#pragma unroll
    for (int kc = 0; kc < 4; kc++) {
        bf16x8 bfr = Wn1F[(kc * 8 + w) * 64 + lane];
#pragma unroll
        for (int mt = 0; mt < 4; mt++)
            acc[mt] = __builtin_amdgcn_mfma_f32_16x16x32_bf16(
                XF[(kc * 4 + mt) * 64 + lane], bfr, acc[mt], 0, 0, 0);
    }

    {   // relu + transpose -> HF (separate buffer: no barrier needed)
        __bf16* HFp = (__bf16*)HF;
        int cw = w * 16 + l16;
        int kc2 = cw >> 5, quad2 = (cw >> 3) & 3, ii = cw & 7;
#pragma unroll
        for (int mt = 0; mt < 4; mt++)
#pragma unroll
            for (int r = 0; r < 4; r++)
                HFp[(((kc2 * 4 + mt) * 64) + quad2 * 16 + quad * 4 + r) * 8 + ii] =
                    (__bf16)fmaxf(acc[mt][r], 0.f);
    }
    __syncthreads();                         // B2: HF ready

    {   // GEMM2 + store: nt = w&3, m-half mh = w>>2
        const int nt = w & 3, mh = w >> 2;
        f32x4 acc2[2];
        float b2 = bn2[nt * 16 + l16];
#pragma unroll
        for (int m = 0; m < 2; m++) { f32x4 v = {b2, b2, b2, b2}; acc2[m] = v; }
#pragma unroll
        for (int kc = 0; kc < 4; kc++) {
            bf16x8 b2f = Wn2F[(kc * 4 + nt) * 64 + lane];
#pragma unroll
            for (int m = 0; m < 2; m++)
                acc2[m] = __builtin_amdgcn_mfma_f32_16x16x32_bf16(
                    HF[(kc * 4 + mh * 2 + m) * 64 + lane], b2f, acc2[m], 0, 0, 0);
        }
#pragma unroll
        for (int m = 0; m < 2; m++)
#pragma unroll
            for (int r = 0; r < 4; r++) {
                int node = n0 + (mh * 2 + m) * 16 + quad * 4 + r;
                if (node < NN)
                    outp[(long)node * 64 + nt * 16 + l16] = acc2[m][r];
            }
    }
}

extern "C" void kernel_launch(void* const* d_in, const int* in_sizes, int n_in,
                              void* d_out, int out_size, void* d_ws, size_t ws_size,
                              hipStream_t stream)
{
    const float* z_h       = (const float*)d_in[0];
    const float* pos_world = (const float*)d_in[1];
    const int*   ei        = (const int*)d_in[2];
    const float* We1 = (const float*)d_in[3];  const float* be1 = (const float*)d_in[4];
    const float* We2 = (const float*)d_in[5];  const float* be2 = (const float*)d_in[6];
    const float* Wg1 = (const float*)d_in[7];  const float* bg1 = (const float*)d_in[8];
    const float* Wg2 = (const float*)d_in[9];  const float* bg2 = (const float*)d_in[10];
    const float* Wn1 = (const float*)d_in[11]; const float* bn1 = (const float*)d_in[12];
    const float* Wn2 = (const float*)d_in[13]; const float* bn2 = (const float*)d_in[14];
    const float* Ww1 = (const float*)d_in[15]; const float* bw1 = (const float*)d_in[16];
    const float* Ww2 = (const float*)d_in[17]; const float* bw2 = (const float*)d_in[18];

    float*  outp    = (float*)d_out;
    float*  m_agg_w = (float*)d_ws;         // 64 floats
    bf16x8* wsF     = (bf16x8*)((char*)d_ws + 256);

    prep<<<(NN * 8 + 255) / 256, 256, 0, stream>>>(
        We1, Wg1, We2, Wn1, Wn2, Ww1, Ww2, wsF, z_h, outp, m_agg_w);
    fused_kernel<<<EBLOCKS4 + WBLOCKS, 512, 0, stream>>>(
        z_h, ei, wsF + WE1F_OFF, wsF + WE2F_OFF,
        be1, be2, bg1, Wg2, bg2,
        pos_world, wsF + WW1F_OFF, wsF + WW2F_OFF, bw1, bw2,
        outp, m_agg_w);
    node_kernel<<<(NN + 63) / 64, 512, 0, stream>>>(
        m_agg_w, wsF + WN1F_OFF, wsF + WN2F_OFF, bn1, bn2, outp);
}

// Round 11
// 297.819 us; speedup vs baseline: 1.9836x; 1.1399x over previous
//
#include <hip/hip_runtime.h>
#include <math.h>

#define NN 50000
#define NE 800000
#define EBLOCKS (NE / 64)          // 12500 edge blocks
#define WBLOCKS ((NN + 63) / 64)   // 782 world blocks

typedef float     f32x4  __attribute__((ext_vector_type(4)));
typedef __bf16    bf16x8 __attribute__((ext_vector_type(8)));
typedef __bf16    bf16x4 __attribute__((ext_vector_type(4)));
typedef _Float16  f16x2  __attribute__((ext_vector_type(2)));
typedef _Float16  f16x4  __attribute__((ext_vector_type(4)));
typedef _Float16  f16x8  __attribute__((ext_vector_type(8)));

// ws layout: [0,256) m_agg_w (64 f32). [256,...) bf16 weight fragments.
#define WE1F_OFF 0        // 5120: We1||Wg1  (kc<5, ct<16)  K 136->160
#define WE2F_OFF 5120     // 1024: We2       (kc<4, ct<4)
#define WN1F_OFF 6144     // 2048: Wn1       (kc<4, ct<8)
#define WN2F_OFF 8192     // 1024: Wn2       (kc<4, ct<4)
#define WW1F_OFF 9216     // 1536: Ww1       (kc<3, ct<8)   K 67->96
#define WW2F_OFF 10752    // 1024: Ww2       (kc<4, ct<4)
#define NCHUNKS  11776

// d_out row n (256 B): first 128 B = f16[64] m_agg accumulator (atomic
// target, zeroed by prep); second 128 B = bf16[64] z_h row n (gather table,
// written by prep). node_kernel block n reads both halves of its rows then
// overwrites them -> race-free, zero extra workspace.

__device__ inline bf16x8 pack8(float4 a, float4 b) {
    bf16x8 r;
    r[0] = (__bf16)a.x; r[1] = (__bf16)a.y; r[2] = (__bf16)a.z; r[3] = (__bf16)a.w;
    r[4] = (__bf16)b.x; r[5] = (__bf16)b.y; r[6] = (__bf16)b.z; r[7] = (__bf16)b.w;
    return r;
}

// packed 2x f16 atomic fadd (global_atomic_pk_add_f16, gfx90a+).
__device__ inline void pk_atomic_add_f16(void* addr, f16x2 v) {
#if __has_builtin(__builtin_amdgcn_global_atomic_fadd_v2f16)
    __builtin_amdgcn_global_atomic_fadd_v2f16((f16x2*)addr, v);
#else
    asm volatile("global_atomic_pk_add_f16 %0, %1, off"
                 :: "v"(addr), "v"(v) : "memory");
#endif
}

// ------- single prep kernel: weight fragments + z-bf16 table + zeroing -----
__global__ __launch_bounds__(256) void prep(
    const float* __restrict__ We1, const float* __restrict__ Wg1,
    const float* __restrict__ We2, const float* __restrict__ Wn1,
    const float* __restrict__ Wn2, const float* __restrict__ Ww1,
    const float* __restrict__ Ww2, bf16x8* __restrict__ wsF,
    const float* __restrict__ z, float* __restrict__ db,
    float* __restrict__ m_agg_w)
{
    const int c = blockIdx.x * 256 + threadIdx.x;

    if (c < 64) m_agg_w[c] = 0.f;

    if (c < NN * 8) {      // z-table (2nd half) + zero f16 acc (1st half)
        int node = c >> 3, q = c & 7;
        const float4* s = (const float4*)(z + (long)node * 64) + q * 2;
        float4 a = s[0], b = s[1];
        *(bf16x8*)((char*)db + (long)node * 256 + 128 + q * 16) = pack8(a, b);
        float4 zz = {0.f, 0.f, 0.f, 0.f};
        *(float4*)((char*)db + (long)node * 256 + q * 16) = zz;
    }

    if (c >= NCHUNKS) return;
    const int lane = c & 63, l16 = lane & 15, row8 = ((lane >> 4) & 3) * 8;
    bf16x8 p;
    if (c < WE2F_OFF) {                       // We1 || Wg1, pad K 136->160
        int ct = (c >> 6) & 15, kc = c >> 10;
        int col = ct * 16 + l16;
        const float* src = (col < 128) ? (We1 + col) : (Wg1 + (col - 128));
#pragma unroll
        for (int i = 0; i < 8; i++) {
            int r = kc * 32 + row8 + i;
            p[i] = (__bf16)((r < 136) ? src[(size_t)r * 128] : 0.f);
        }
    } else if (c < WN1F_OFF) {
        int cc = c - WE2F_OFF; int ct = (cc >> 6) & 3, kc = cc >> 8;
        int col = ct * 16 + l16;
#pragma unroll
        for (int i = 0; i < 8; i++)
            p[i] = (__bf16)We2[(size_t)(kc * 32 + row8 + i) * 64 + col];
    } else if (c < WN2F_OFF) {
        int cc = c - WN1F_OFF; int ct = (cc >> 6) & 7, kc = cc >> 9;
        int col = ct * 16 + l16;
#pragma unroll
        for (int i = 0; i < 8; i++)
            p[i] = (__bf16)Wn1[(size_t)(kc * 32 + row8 + i) * 128 + col];
    } else if (c < WW1F_OFF) {
        int cc = c - WN2F_OFF; int ct = (cc >> 6) & 3, kc = cc >> 8;
        int col = ct * 16 + l16;
#pragma unroll
        for (int i = 0; i < 8; i++)
            p[i] = (__bf16)Wn2[(size_t)(kc * 32 + row8 + i) * 64 + col];
    } else if (c < WW2F_OFF) {                // Ww1, pad K 67->96
        int cc = c - WW1F_OFF; int ct = (cc >> 6) & 7, kc = cc >> 9;
        int col = ct * 16 + l16;
#pragma unroll
        for (int i = 0; i < 8; i++) {
            int r = kc * 32 + row8 + i;
            p[i] = (__bf16)((r < 67) ? Ww1[(size_t)r * 128 + col] : 0.f);
        }
    } else {
        int cc = c - WW2F_OFF; int ct = (cc >> 6) & 3, kc = cc >> 8;
        int col = ct * 16 + l16;
#pragma unroll
        for (int i = 0; i < 8; i++)
            p[i] = (__bf16)Ww2[(size_t)(kc * 32 + row8 + i) * 64 + col];
    }
    wsF[c] = p;
}

// --------- fused edge + world kernel: blocks [0,EBLOCKS) = edges, rest = world
// Edge path (R11 = R8 shell + tr-read GEMM2): GEMM1 unchanged. H is written
// in a tr-subtiled layout with ONE b64 write per (mt,nt) (was 32 scattered
// b16). GEMM2 is operand-swapped (D = We2^T H^T, swap proven in R2) across
// ALL 8 waves, B-frags loaded via ds_read_b64_tr_b16 (hw transpose); D is
// edge-per-lane so sigmoid is per-thread and M-pack is one b64 write.
// tr layout (bf16 idx, region (kc,et) at (kc*4+et)*512):
//   H[kc*32+h32][et*16+e16] at ((h32>>2)&1)*256 + (h32>>3)*64 + (h32&3)*16 + e16
// which inverts the HW read: lane l elem j <- base + (l&15) + j*16 + (l>>4)*64.
union FusedLds {
    bf16x8 XF[1280];                                   // edge XF 20 KB
    struct {
        bf16x8   HF[1024];                             // 16 KB (tr-subtiled)
        _Float16 M[64 * 68];                           // 8.7 KB, stride 68
    } s;
};

__global__ __launch_bounds__(512, 6) void fused_kernel(
    const float* __restrict__ z_h, const int* __restrict__ ei,
    const bf16x8* __restrict__ We1F, const bf16x8* __restrict__ We2F,
    const float* __restrict__ be1, const float* __restrict__ be2,
    const float* __restrict__ bg1, const float* __restrict__ Wg2,
    const float* __restrict__ bg2,
    const float* __restrict__ pos_world,
    const bf16x8* __restrict__ Ww1F, const bf16x8* __restrict__ Ww2F,
    const float* __restrict__ bw1, const float* __restrict__ bw2,
    float* __restrict__ magg_rows,     // = d_out; acc first half, z-bf16 second
    float* __restrict__ m_agg_w)
{
    __shared__ FusedLds U;
    __shared__ int   tgt_s[64];
    __shared__ float gred[4][64];

    const int t = threadIdx.x;               // 0..511
    const int lane = t & 63, w = t >> 6;     // w 0..7
    const int quad = lane >> 4, l16 = lane & 15;

    if (blockIdx.x >= EBLOCKS) {
        // ================= world path (unchanged R8) ========================
        const int n0 = (blockIdx.x - EBLOCKS) * 64;
        {   // gather
            int nn = t >> 3, q = t & 7;
            int mt = nn >> 4, l16e = nn & 15;
            int node = n0 + nn; if (node >= NN) node = NN - 1;
            if (q < 4) {
                const float4* zr = (const float4*)(z_h + (long)node * 64) + q * 4;
                float4 a0 = zr[0], a1 = zr[1], a2 = zr[2], a3 = zr[3];
                int kcs = q >> 1, qa = (q & 1) * 2;
                U.XF[(kcs * 4 + mt) * 64 + qa * 16 + l16e]       = pack8(a0, a1);
                U.XF[(kcs * 4 + mt) * 64 + (qa + 1) * 16 + l16e] = pack8(a2, a3);
            } else if (q == 4) {
                float4 a0 = *(const float4*)(z_h + (long)node * 64);
                bf16x8 f;
#pragma unroll
                for (int i = 0; i < 8; i++) f[i] = (__bf16)0.f;
                f[0] = (__bf16)(a0.x - pos_world[0]);
                f[1] = (__bf16)(a0.y - pos_world[1]);
                f[2] = (__bf16)(a0.z - pos_world[2]);
                U.XF[(8 + mt) * 64 + l16e] = f;
            } else {
                bf16x8 z;
#pragma unroll
                for (int i = 0; i < 8; i++) z[i] = (__bf16)0.f;
                U.XF[(8 + mt) * 64 + (q - 4) * 16 + l16e] = z;
            }
        }
        __syncthreads();

        f32x4 acc[4];
        {
            float b = bw1[w * 16 + l16];
#pragma unroll
            for (int mt = 0; mt < 4; mt++) { f32x4 v = {b, b, b, b}; acc[mt] = v; }
        }
#pragma unroll
        for (int kc = 0; kc < 3; kc++) {
            bf16x8 bfr = Ww1F[(kc * 8 + w) * 64 + lane];
#pragma unroll
            for (int mt = 0; mt < 4; mt++)
                acc[mt] = __builtin_amdgcn_mfma_f32_16x16x32_bf16(
                    U.XF[(kc * 4 + mt) * 64 + lane], bfr, acc[mt], 0, 0, 0);
        }
        __syncthreads();

        {   // relu + transpose -> HF (old GEMM2-A order, world only)
            __bf16* HFp = (__bf16*)U.s.HF;
            int cw = w * 16 + l16;
            int kc2 = cw >> 5, quad2 = (cw >> 3) & 3, ii = cw & 7;
#pragma unroll
            for (int mt = 0; mt < 4; mt++)
#pragma unroll
                for (int r = 0; r < 4; r++)
                    HFp[(((kc2 * 4 + mt) * 64) + quad2 * 16 + quad * 4 + r) * 8 + ii] =
                        (__bf16)fmaxf(acc[mt][r], 0.f);
        }
        __syncthreads();

        {   // GEMM2 + masked column-sum
            const int nt = w & 3, mh = w >> 2;
            f32x4 acc2[2];
            float b2 = bw2[nt * 16 + l16];
#pragma unroll
            for (int m = 0; m < 2; m++) { f32x4 v = {b2, b2, b2, b2}; acc2[m] = v; }
#pragma unroll
            for (int kc = 0; kc < 4; kc++) {
                bf16x8 b2f = Ww2F[(kc * 4 + nt) * 64 + lane];
#pragma unroll
                for (int m = 0; m < 2; m++)
                    acc2[m] = __builtin_amdgcn_mfma_f32_16x16x32_bf16(
                        U.s.HF[(kc * 4 + mh * 2 + m) * 64 + lane], b2f, acc2[m], 0, 0, 0);
            }
            float s = 0.f;
#pragma unroll
            for (int m = 0; m < 2; m++)
#pragma unroll
                for (int r = 0; r < 4; r++) {
                    int node = n0 + (mh * 2 + m) * 16 + quad * 4 + r;
                    s += (node < NN) ? acc2[m][r] : 0.f;
                }
            s += __shfl_xor(s, 16, 64);
            s += __shfl_xor(s, 32, 64);
            if (quad == 0) atomicAdd(m_agg_w + nt * 16 + l16, s);
        }
        return;
    }

    // ================= edge path (64 edges/block, bf16 table gather) ========
    const int e0 = blockIdx.x * 64;          // NE % 64 == 0

    {   // ---- gather: 8 threads/edge, thread q loads 16B chunk q of BOTH rows
        const int ee = t >> 3, q = t & 7;
        const int mt = ee >> 4, l16e = ee & 15;
        const int eg = e0 + ee;
        const int rs = ei[eg], rt = ei[NE + eg];
        const bf16x8* zs = (const bf16x8*)((const char*)magg_rows + (long)rs * 256 + 128);
        const bf16x8* zt = (const bf16x8*)((const char*)magg_rows + (long)rt * 256 + 128);
        bf16x8 sa = zs[q];                   // src cols q*8 .. q*8+7
        bf16x8 ta = zt[q];                   // tgt cols q*8 .. q*8+7
        const int kcs = q >> 2, qslot = q & 3;
        U.XF[(kcs * 4 + mt) * 64 + qslot * 16 + l16e]       = sa;
        U.XF[((kcs + 2) * 4 + mt) * 64 + qslot * 16 + l16e] = ta;
        if (q == 4) tgt_s[ee] = rt;
        if (q == 0) {        // edge features (cols 128..135) from bf16 chunk 0
            float dx = (float)sa[0] - (float)ta[0];
            float dy = (float)sa[1] - (float)ta[1];
            float dz = (float)sa[2] - (float)ta[2];
            float ax = (float)sa[3], ay = (float)sa[4], az = (float)sa[5];
            float bx = (float)ta[3], by = (float)ta[4], bz = (float)ta[5];
            float cx = ay * bz - az * by;
            float cy = az * bx - ax * bz;
            float cz = ax * by - ay * bx;
            bf16x8 f;
            f[0] = (__bf16)dx; f[1] = (__bf16)dy; f[2] = (__bf16)dz;
            f[3] = (__bf16)(dx * dx + dy * dy + dz * dz);
            f[4] = (__bf16)cx; f[5] = (__bf16)cy; f[6] = (__bf16)cz;
            f[7] = (__bf16)sqrtf(cx * cx + cy * cy + cz * cz);
            U.XF[(16 + mt) * 64 + l16e] = f;
        } else if (q >= 5) { // zero pad (cols 136..159)
            bf16x8 z;
#pragma unroll
            for (int i = 0; i < 8; i++) z[i] = (__bf16)0.f;
            U.XF[(16 + mt) * 64 + (q - 4) * 16 + l16e] = z;
        }
    }
    __syncthreads();                         // B1: XF + tgt_s ready

    // ---- GEMM1: wave owns 32 cols (tiles 2w, 2w+1), 1-ahead B prefetch ----
    f32x4 acc[4][2];
#pragma unroll
    for (int nt = 0; nt < 2; nt++) {
        int col = (w * 2 + nt) * 16 + l16;
        float b = (col < 128) ? be1[col] : bg1[col - 128];
#pragma unroll
        for (int mt = 0; mt < 4; mt++) { f32x4 v = {b, b, b, b}; acc[mt][nt] = v; }
    }
    bf16x8 bcur0 = We1F[(w * 2) * 64 + lane];
    bf16x8 bcur1 = We1F[(w * 2 + 1) * 64 + lane];
#pragma unroll
    for (int kc = 0; kc < 5; kc++) {
        bf16x8 bnx0, bnx1;
        if (kc < 4) {
            bnx0 = We1F[((kc + 1) * 16 + w * 2) * 64 + lane];
            bnx1 = We1F[((kc + 1) * 16 + w * 2 + 1) * 64 + lane];
        }
#pragma unroll
        for (int mt = 0; mt < 4; mt++) {
            bf16x8 af = U.XF[(kc * 4 + mt) * 64 + lane];
            acc[mt][0] = __builtin_amdgcn_mfma_f32_16x16x32_bf16(af, bcur0, acc[mt][0], 0, 0, 0);
            acc[mt][1] = __builtin_amdgcn_mfma_f32_16x16x32_bf16(af, bcur1, acc[mt][1], 0, 0, 0);
        }
        bcur0 = bnx0; bcur1 = bnx1;
    }
    __syncthreads();                         // B2: XF reads done (HF may overwrite)

    if (w < 4) {
        // ---- message waves: relu -> tr-subtiled HF, ONE b64 write/(mt,nt) --
        __bf16* HFb = (__bf16*)U.s.HF;
#pragma unroll
        for (int nt = 0; nt < 2; nt++) {
            int h = (w * 2 + nt) * 16 + l16;       // 0..127 (msg cols)
            int kc2 = h >> 5, h32 = h & 31;
            int idx0 = kc2 * 2048 + ((h32 >> 2) & 1) * 256 + (h32 >> 3) * 64
                     + (h32 & 3) * 16 + quad * 4;  // + mt*512
#pragma unroll
            for (int mt = 0; mt < 4; mt++) {
                bf16x4 hv;
#pragma unroll
                for (int r = 0; r < 4; r++)
                    hv[r] = (__bf16)fmaxf(acc[mt][nt][r], 0.f);
                *(bf16x4*)(HFb + idx0 + mt * 512) = hv;
            }
        }
    } else {
        // ---- gate waves: in-register partials over their 32 gate cols ----
        float gp[4][4];
#pragma unroll
        for (int mt = 0; mt < 4; mt++)
#pragma unroll
            for (int r = 0; r < 4; r++) gp[mt][r] = 0.f;
#pragma unroll
        for (int nt = 0; nt < 2; nt++) {
            float wg = Wg2[((w - 4) * 2 + nt) * 16 + l16];
#pragma unroll
            for (int mt = 0; mt < 4; mt++)
#pragma unroll
                for (int r = 0; r < 4; r++)
                    gp[mt][r] += fmaxf(acc[mt][nt][r], 0.f) * wg;
        }
#pragma unroll
        for (int mask = 1; mask < 16; mask <<= 1)
#pragma unroll
            for (int mt = 0; mt < 4; mt++)
#pragma unroll
                for (int r = 0; r < 4; r++)
                    gp[mt][r] += __shfl_xor(gp[mt][r], mask, 64);
        if (l16 == 0) {
#pragma unroll
            for (int mt = 0; mt < 4; mt++)
#pragma unroll
                for (int r = 0; r < 4; r++)
                    gred[(w - 4) & 3][mt * 16 + quad * 4 + r] = gp[mt][r];
        }
    }
    __syncthreads();                         // B3: HF + gred ready

    // ---- GEMM2 (ALL 8 waves, swapped): D[mc][e] = We2^T H^T via tr_read ----
    {
        const int mct = w & 3, et0 = (w >> 2) * 2;
        f32x4 acc2[2];
        {
            float4 b4 = *(const float4*)(be2 + mct * 16 + quad * 4);
            f32x4 v; v[0] = b4.x; v[1] = b4.y; v[2] = b4.z; v[3] = b4.w;
            acc2[0] = v; acc2[1] = v;
        }
        const char* hb = (const char*)U.s.HF;
#pragma unroll
        for (int kc = 0; kc < 4; kc++) {
            bf16x8 a2 = We2F[(kc * 4 + mct) * 64 + lane];
            union { unsigned long long u; __bf16 h[4]; } t0, t1, t2, t3;
            unsigned b0 = (unsigned)(unsigned long long)(hb + (kc * 4 + et0) * 1024);
            unsigned b1 = b0 + 512;
            unsigned b2 = (unsigned)(unsigned long long)(hb + (kc * 4 + et0 + 1) * 1024);
            unsigned b3 = b2 + 512;
            // 4 hw-transpose reads; internal lgkmcnt(0) makes results ready
            // before the asm block exits (no hoist hazard).
            asm volatile(
                "ds_read_b64_tr_b16 %0, %4\n\t"
                "ds_read_b64_tr_b16 %1, %5\n\t"
                "ds_read_b64_tr_b16 %2, %6\n\t"
                "ds_read_b64_tr_b16 %3, %7\n\t"
                "s_waitcnt lgkmcnt(0)"
                : "=&v"(t0.u), "=&v"(t1.u), "=&v"(t2.u), "=&v"(t3.u)
                : "v"(b0), "v"(b1), "v"(b2), "v"(b3));
            bf16x8 f0, f1;
#pragma unroll
            for (int i = 0; i < 4; i++) {
                f0[i] = t0.h[i]; f0[4 + i] = t1.h[i];
                f1[i] = t2.h[i]; f1[4 + i] = t3.h[i];
            }
            acc2[0] = __builtin_amdgcn_mfma_f32_16x16x32_bf16(a2, f0, acc2[0], 0, 0, 0);
            acc2[1] = __builtin_amdgcn_mfma_f32_16x16x32_bf16(a2, f1, acc2[1], 0, 0, 0);
        }

        // ---- per-thread sigmoid + weighted M write (one b64 per et) ----
#pragma unroll
        for (int m = 0; m < 2; m++) {
            int edge = (et0 + m) * 16 + l16;
            float g = bg2[0] + gred[0][edge] + gred[1][edge]
                             + gred[2][edge] + gred[3][edge];
            float wg = 1.f / (1.f + __expf(-g));
            f16x4 hv;
#pragma unroll
            for (int r = 0; r < 4; r++)
                hv[r] = (_Float16)(acc2[m][r] * wg);
            *(f16x4*)((char*)U.s.M + edge * 136 + (mct * 16 + quad * 4) * 2) = hv;
        }
    }
    __syncthreads();                         // B4: M ready

    // ---- scatter: all 8 waves, packed v2f16 atomics ----
    // thread t, step k: edge = (t>>5) + 16k, pair p = t&31.
    // per wave-instr: 2 rows x 128 B = 4 cachelines x 16 lanes.
    {
        const int p = t & 31, eb = t >> 5;
        char* base = (char*)magg_rows;
#pragma unroll
        for (int k = 0; k < 4; k++) {
            int e = eb + k * 16;
            f16x2 v = *(const f16x2*)&U.s.M[e * 68 + p * 2];
            pk_atomic_add_f16(base + (long)tgt_s[e] * 256 + p * 4, v);
        }
    }
}

// ---------------- node kernel: 512 thr, 2 barriers (separate XF/HF) --------
__global__ __launch_bounds__(512, 4) void node_kernel(
    const float* __restrict__ m_agg_w,
    const bf16x8* __restrict__ Wn1F, const bf16x8* __restrict__ Wn2F,
    const float* __restrict__ bn1, const float* __restrict__ bn2,
    float* __restrict__ outp)     // rows: f16 acc | bf16 z, then output
{
    __shared__ bf16x8 XF[1024];   // 16 KB
    __shared__ bf16x8 HF[1024];   // 16 KB (separate -> no XF/HF hazard barrier)
    const int t = threadIdx.x;
    const int n0 = blockIdx.x * 64;
    const int lane = t & 63, w = t >> 6;
    const int quad = lane >> 4, l16 = lane & 15;

    {   // gather: 8 threads/node; halves: z-bf16 | m_agg(f16) + m_agg_w
        int nn = t >> 3, q = t & 7;
        int mt = nn >> 4, l16e = nn & 15;
        int node = n0 + nn; if (node >= NN) node = NN - 1;
        int half = q >> 2, sub = q & 3;
        bf16x8 c0, c1;
        if (half == 0) {
            const bf16x8* zr = (const bf16x8*)((const char*)outp + (long)node * 256 + 128) + sub * 2;
            c0 = zr[0]; c1 = zr[1];
        } else {
            const f16x8* mr = (const f16x8*)((const char*)outp + (long)node * 256) + sub * 2;
            f16x8 r0 = mr[0], r1 = mr[1];
            const float* mw = m_agg_w + sub * 16;
#pragma unroll
            for (int i = 0; i < 8; i++) {
                c0[i] = (__bf16)((float)r0[i] + mw[i]);
                c1[i] = (__bf16)((float)r1[i] + mw[i + 8]);
            }
        }
        int kcs = (sub >> 1) + half * 2, qa = (sub & 1) * 2;
        XF[(kcs * 4 + mt) * 64 + qa * 16 + l16e]       = c0;
        XF[(kcs * 4 + mt) * 64 + (qa + 1) * 16 + l16e] = c1;
    }
    __syncthreads();                         // B1: XF ready

    f32x4 acc[4];
    {
        float b = bn1[w * 16 + l16];
#pragma unroll
        for (int mt = 0; mt < 4; mt++) { f32x4 v = {b, b, b, b}; acc[mt] = v; }
    }
#pragma unroll
    for (int kc = 0; kc < 4; kc++) {
        bf16x8 bfr = Wn1F[(kc * 8 + w) * 64 + lane];
#pragma unroll
        for (int mt = 0; mt < 4; mt++)
            acc[mt] = __builtin_amdgcn_mfma_f32_16x16x32_bf16(
                XF[(kc * 4 + mt) * 64 + lane], bfr, acc[mt], 0, 0, 0);
    }

    {   // relu + transpose -> HF (separate buffer: no barrier needed)
        __bf16* HFp = (__bf16*)HF;
        int cw = w * 16 + l16;
        int kc2 = cw >> 5, quad2 = (cw >> 3) & 3, ii = cw & 7;
#pragma unroll
        for (int mt = 0; mt < 4; mt++)
#pragma unroll
            for (int r = 0; r < 4; r++)
                HFp[(((kc2 * 4 + mt) * 64) + quad2 * 16 + quad * 4 + r) * 8 + ii] =
                    (__bf16)fmaxf(acc[mt][r], 0.f);
    }
    __syncthreads();                         // B2: HF ready

    {   // GEMM2 + store: nt = w&3, m-half mh = w>>2
        const int nt = w & 3, mh = w >> 2;
        f32x4 acc2[2];
        float b2 = bn2[nt * 16 + l16];
#pragma unroll
        for (int m = 0; m < 2; m++) { f32x4 v = {b2, b2, b2, b2}; acc2[m] = v; }
#pragma unroll
        for (int kc = 0; kc < 4; kc++) {
            bf16x8 b2f = Wn2F[(kc * 4 + nt) * 64 + lane];
#pragma unroll
            for (int m = 0; m < 2; m++)
                acc2[m] = __builtin_amdgcn_mfma_f32_16x16x32_bf16(
                    HF[(kc * 4 + mh * 2 + m) * 64 + lane], b2f, acc2[m], 0, 0, 0);
        }
#pragma unroll
        for (int m = 0; m < 2; m++)
#pragma unroll
            for (int r = 0; r < 4; r++) {
                int node = n0 + (mh * 2 + m) * 16 + quad * 4 + r;
                if (node < NN)
                    outp[(long)node * 64 + nt * 16 + l16] = acc2[m][r];
            }
    }
}

extern "C" void kernel_launch(void* const* d_in, const int* in_sizes, int n_in,
                              void* d_out, int out_size, void* d_ws, size_t ws_size,
                              hipStream_t stream)
{
    const float* z_h       = (const float*)d_in[0];
    const float* pos_world = (const float*)d_in[1];
    const int*   ei        = (const int*)d_in[2];
    const float* We1 = (const float*)d_in[3];  const float* be1 = (const float*)d_in[4];
    const float* We2 = (const float*)d_in[5];  const float* be2 = (const float*)d_in[6];
    const float* Wg1 = (const float*)d_in[7];  const float* bg1 = (const float*)d_in[8];
    const float* Wg2 = (const float*)d_in[9];  const float* bg2 = (const float*)d_in[10];
    const float* Wn1 = (const float*)d_in[11]; const float* bn1 = (const float*)d_in[12];
    const float* Wn2 = (const float*)d_in[13]; const float* bn2 = (const float*)d_in[14];
    const float* Ww1 = (const float*)d_in[15]; const float* bw1 = (const float*)d_in[16];
    const float* Ww2 = (const float*)d_in[17]; const float* bw2 = (const float*)d_in[18];

    float*  outp    = (float*)d_out;
    float*  m_agg_w = (float*)d_ws;         // 64 floats
    bf16x8* wsF     = (bf16x8*)((char*)d_ws + 256);

    prep<<<(NN * 8 + 255) / 256, 256, 0, stream>>>(
        We1, Wg1, We2, Wn1, Wn2, Ww1, Ww2, wsF, z_h, outp, m_agg_w);
    fused_kernel<<<EBLOCKS + WBLOCKS, 512, 0, stream>>>(
        z_h, ei, wsF + WE1F_OFF, wsF + WE2F_OFF,
        be1, be2, bg1, Wg2, bg2,
        pos_world, wsF + WW1F_OFF, wsF + WW2F_OFF, bw1, bw2,
        outp, m_agg_w);
    node_kernel<<<(NN + 63) / 64, 512, 0, stream>>>(
        m_agg_w, wsF + WN1F_OFF, wsF + WN2F_OFF, bn1, bn2, outp);
}

// Round 12
// 264.052 us; speedup vs baseline: 2.2373x; 1.1279x over previous
//
#include <hip/hip_runtime.h>
#include <math.h>

#define NN 50000
#define NE 800000
#define EBLOCKS (NE / 32)          // 25000 edge blocks (32 edges, 256 thr)
#define WBLOCKS ((NN + 63) / 64)   // 782 world blocks

typedef float     f32x4  __attribute__((ext_vector_type(4)));
typedef __bf16    bf16x8 __attribute__((ext_vector_type(8)));
typedef _Float16  f16x2  __attribute__((ext_vector_type(2)));
typedef _Float16  f16x8  __attribute__((ext_vector_type(8)));

// ws layout: [0,256) m_agg_w (64 f32). [256,...) bf16 weight fragments.
#define WE1F_OFF 0        // 5120: We1||Wg1  (kc<5, ct<16)  K 136->160
#define WE2F_OFF 5120     // 1024: We2       (kc<4, ct<4)
#define WN1F_OFF 6144     // 2048: Wn1       (kc<4, ct<8)
#define WN2F_OFF 8192     // 1024: Wn2       (kc<4, ct<4)
#define WW1F_OFF 9216     // 1536: Ww1       (kc<3, ct<8)   K 67->96
#define WW2F_OFF 10752    // 1024: Ww2       (kc<4, ct<4)
#define NCHUNKS  11776

// d_out row n (256 B): first 128 B = f16[64] m_agg accumulator (atomic
// target, zeroed by prep); second 128 B = bf16[64] z_h row n (gather table,
// written by prep). node_kernel block n reads both halves of its rows then
// overwrites them -> race-free, zero extra workspace.

__device__ inline bf16x8 pack8(float4 a, float4 b) {
    bf16x8 r;
    r[0] = (__bf16)a.x; r[1] = (__bf16)a.y; r[2] = (__bf16)a.z; r[3] = (__bf16)a.w;
    r[4] = (__bf16)b.x; r[5] = (__bf16)b.y; r[6] = (__bf16)b.z; r[7] = (__bf16)b.w;
    return r;
}

// packed 2x f16 atomic fadd (global_atomic_pk_add_f16, gfx90a+).
__device__ inline void pk_atomic_add_f16(void* addr, f16x2 v) {
#if __has_builtin(__builtin_amdgcn_global_atomic_fadd_v2f16)
    __builtin_amdgcn_global_atomic_fadd_v2f16((f16x2*)addr, v);
#else
    asm volatile("global_atomic_pk_add_f16 %0, %1, off"
                 :: "v"(addr), "v"(v) : "memory");
#endif
}

// ------- single prep kernel: weight fragments + z-bf16 table + zeroing -----
__global__ __launch_bounds__(256) void prep(
    const float* __restrict__ We1, const float* __restrict__ Wg1,
    const float* __restrict__ We2, const float* __restrict__ Wn1,
    const float* __restrict__ Wn2, const float* __restrict__ Ww1,
    const float* __restrict__ Ww2, bf16x8* __restrict__ wsF,
    const float* __restrict__ z, float* __restrict__ db,
    float* __restrict__ m_agg_w)
{
    const int c = blockIdx.x * 256 + threadIdx.x;

    if (c < 64) m_agg_w[c] = 0.f;

    if (c < NN * 8) {      // z-table (2nd half) + zero f16 acc (1st half)
        int node = c >> 3, q = c & 7;
        const float4* s = (const float4*)(z + (long)node * 64) + q * 2;
        float4 a = s[0], b = s[1];
        *(bf16x8*)((char*)db + (long)node * 256 + 128 + q * 16) = pack8(a, b);
        float4 zz = {0.f, 0.f, 0.f, 0.f};
        *(float4*)((char*)db + (long)node * 256 + q * 16) = zz;
    }

    if (c >= NCHUNKS) return;
    const int lane = c & 63, l16 = lane & 15, row8 = ((lane >> 4) & 3) * 8;
    bf16x8 p;
    if (c < WE2F_OFF) {                       // We1 || Wg1, pad K 136->160
        int ct = (c >> 6) & 15, kc = c >> 10;
        int col = ct * 16 + l16;
        const float* src = (col < 128) ? (We1 + col) : (Wg1 + (col - 128));
#pragma unroll
        for (int i = 0; i < 8; i++) {
            int r = kc * 32 + row8 + i;
            p[i] = (__bf16)((r < 136) ? src[(size_t)r * 128] : 0.f);
        }
    } else if (c < WN1F_OFF) {
        int cc = c - WE2F_OFF; int ct = (cc >> 6) & 3, kc = cc >> 8;
        int col = ct * 16 + l16;
#pragma unroll
        for (int i = 0; i < 8; i++)
            p[i] = (__bf16)We2[(size_t)(kc * 32 + row8 + i) * 64 + col];
    } else if (c < WN2F_OFF) {
        int cc = c - WN1F_OFF; int ct = (cc >> 6) & 7, kc = cc >> 9;
        int col = ct * 16 + l16;
#pragma unroll
        for (int i = 0; i < 8; i++)
            p[i] = (__bf16)Wn1[(size_t)(kc * 32 + row8 + i) * 128 + col];
    } else if (c < WW1F_OFF) {
        int cc = c - WN2F_OFF; int ct = (cc >> 6) & 3, kc = cc >> 8;
        int col = ct * 16 + l16;
#pragma unroll
        for (int i = 0; i < 8; i++)
            p[i] = (__bf16)Wn2[(size_t)(kc * 32 + row8 + i) * 64 + col];
    } else if (c < WW2F_OFF) {                // Ww1, pad K 67->96
        int cc = c - WW1F_OFF; int ct = (cc >> 6) & 7, kc = cc >> 9;
        int col = ct * 16 + l16;
#pragma unroll
        for (int i = 0; i < 8; i++) {
            int r = kc * 32 + row8 + i;
            p[i] = (__bf16)((r < 67) ? Ww1[(size_t)r * 128 + col] : 0.f);
        }
    } else {
        int cc = c - WW2F_OFF; int ct = (cc >> 6) & 3, kc = cc >> 8;
        int col = ct * 16 + l16;
#pragma unroll
        for (int i = 0; i < 8; i++)
            p[i] = (__bf16)Ww2[(size_t)(kc * 32 + row8 + i) * 64 + col];
    }
    wsF[c] = p;
}

// --------- fused edge + world kernel: blocks [0,EBLOCKS) = edges, rest = world
// Edge path (R12): 32 edges/block, 256 threads (4 waves) -> up to 6 blocks/CU
// resident (vs 4-block cap of 8-wave blocks). Wave owns 2 msg + 2 gate
// GEMM1 col-tiles; all 4 waves work in every phase (no idle halves). Gather,
// HF transpose, sigmoid-from-gred, and scatter batching are R8-verbatim
// patterns scaled to 32 edges. World path: R7's 256-thread variant.
union FusedLds {
    bf16x8 XF[1024];                    // world gather 12 tiles / world HF 16 KB
    struct {
        bf16x8   HF[512];               // edge HF 8 KB (aliases dead XF)
        _Float16 M[32 * 68];            // 4.4 KB
    } s;
};

__global__ __launch_bounds__(256, 6) void fused_kernel(
    const float* __restrict__ z_h, const int* __restrict__ ei,
    const bf16x8* __restrict__ We1F, const bf16x8* __restrict__ We2F,
    const float* __restrict__ be1, const float* __restrict__ be2,
    const float* __restrict__ bg1, const float* __restrict__ Wg2,
    const float* __restrict__ bg2,
    const float* __restrict__ pos_world,
    const bf16x8* __restrict__ Ww1F, const bf16x8* __restrict__ Ww2F,
    const float* __restrict__ bw1, const float* __restrict__ bw2,
    float* __restrict__ magg_rows,     // = d_out; acc first half, z-bf16 second
    float* __restrict__ m_agg_w)
{
    __shared__ FusedLds U;
    __shared__ int   tgt_s[32];
    __shared__ float gred[4][32];

    const int t = threadIdx.x;               // 0..255
    const int lane = t & 63, w = t >> 6;     // w 0..3
    const int quad = lane >> 4, l16 = lane & 15;

    if (blockIdx.x >= EBLOCKS) {
        // ================= world path (R7 256-thread, 64 nodes) =============
        const int n0 = (blockIdx.x - EBLOCKS) * 64;
        {   // gather: 4 threads/node
            int nn = t >> 2, q = t & 3;
            int mt = nn >> 4, l16e = nn & 15;
            int node = n0 + nn; if (node >= NN) node = NN - 1;
            const float4* zr = (const float4*)(z_h + (long)node * 64) + q * 4;
            float4 a0 = zr[0], a1 = zr[1], a2 = zr[2], a3 = zr[3];
            int kcs = q >> 1, qa = (q & 1) * 2;
            U.XF[(kcs * 4 + mt) * 64 + qa * 16 + l16e]       = pack8(a0, a1);
            U.XF[(kcs * 4 + mt) * 64 + (qa + 1) * 16 + l16e] = pack8(a2, a3);
            if (q == 0) {
                bf16x8 f;
#pragma unroll
                for (int i = 0; i < 8; i++) f[i] = (__bf16)0.f;
                f[0] = (__bf16)(a0.x - pos_world[0]);
                f[1] = (__bf16)(a0.y - pos_world[1]);
                f[2] = (__bf16)(a0.z - pos_world[2]);
                U.XF[(8 + mt) * 64 + l16e] = f;
            } else {
                bf16x8 z8;
#pragma unroll
                for (int i = 0; i < 8; i++) z8[i] = (__bf16)0.f;
                U.XF[(8 + mt) * 64 + q * 16 + l16e] = z8;
            }
        }
        __syncthreads();

        f32x4 acc[4][2];
#pragma unroll
        for (int nt2 = 0; nt2 < 2; nt2++) {
            float b = bw1[(w * 2 + nt2) * 16 + l16];
#pragma unroll
            for (int mt = 0; mt < 4; mt++) { f32x4 v = {b, b, b, b}; acc[mt][nt2] = v; }
        }
#pragma unroll
        for (int kc = 0; kc < 3; kc++) {
#pragma unroll
            for (int nt2 = 0; nt2 < 2; nt2++) {
                bf16x8 bfr = Ww1F[(kc * 8 + w * 2 + nt2) * 64 + lane];
#pragma unroll
                for (int mt = 0; mt < 4; mt++)
                    acc[mt][nt2] = __builtin_amdgcn_mfma_f32_16x16x32_bf16(
                        U.XF[(kc * 4 + mt) * 64 + lane], bfr, acc[mt][nt2], 0, 0, 0);
            }
        }
        __syncthreads();

        {   // relu + transpose -> HF (aliases XF base)
            __bf16* HFp = (__bf16*)U.XF;
#pragma unroll
            for (int nt2 = 0; nt2 < 2; nt2++) {
                int cw = (w * 2 + nt2) * 16 + l16;
                int kc2 = cw >> 5, quad2 = (cw >> 3) & 3, ii = cw & 7;
#pragma unroll
                for (int mt = 0; mt < 4; mt++)
#pragma unroll
                    for (int r = 0; r < 4; r++)
                        HFp[(((kc2 * 4 + mt) * 64) + quad2 * 16 + quad * 4 + r) * 8 + ii] =
                            (__bf16)fmaxf(acc[mt][nt2][r], 0.f);
            }
        }
        __syncthreads();

        {   // GEMM2 + masked column-sum (wave w = col-tile, mh loop)
            f32x4 acc2[2][2];
            float b2 = bw2[w * 16 + l16];
#pragma unroll
            for (int mh = 0; mh < 2; mh++)
#pragma unroll
                for (int m = 0; m < 2; m++) { f32x4 v = {b2, b2, b2, b2}; acc2[mh][m] = v; }
#pragma unroll
            for (int kc = 0; kc < 4; kc++) {
                bf16x8 b2f = Ww2F[(kc * 4 + w) * 64 + lane];
#pragma unroll
                for (int mh = 0; mh < 2; mh++)
#pragma unroll
                    for (int m = 0; m < 2; m++)
                        acc2[mh][m] = __builtin_amdgcn_mfma_f32_16x16x32_bf16(
                            U.XF[(kc * 4 + mh * 2 + m) * 64 + lane], b2f, acc2[mh][m], 0, 0, 0);
            }
            float s = 0.f;
#pragma unroll
            for (int mh = 0; mh < 2; mh++)
#pragma unroll
                for (int m = 0; m < 2; m++)
#pragma unroll
                    for (int r = 0; r < 4; r++) {
                        int node = n0 + (mh * 2 + m) * 16 + quad * 4 + r;
                        s += (node < NN) ? acc2[mh][m][r] : 0.f;
                    }
            s += __shfl_xor(s, 16, 64);
            s += __shfl_xor(s, 32, 64);
            if (quad == 0) atomicAdd(m_agg_w + w * 16 + l16, s);
        }
        return;
    }

    // ================= edge path (32 edges/block, bf16 table gather) ========
    const int e0 = blockIdx.x * 32;          // NE % 32 == 0

    {   // ---- gather: 8 threads/edge, thread q loads 16B chunk q of BOTH rows
        const int ee = t >> 3, q = t & 7;    // ee 0..31
        const int mt = ee >> 4, l16e = ee & 15;
        const int eg = e0 + ee;
        const int rs = ei[eg], rt = ei[NE + eg];
        const bf16x8* zs = (const bf16x8*)((const char*)magg_rows + (long)rs * 256 + 128);
        const bf16x8* zt = (const bf16x8*)((const char*)magg_rows + (long)rt * 256 + 128);
        bf16x8 sa = zs[q];                   // src cols q*8 .. q*8+7
        bf16x8 ta = zt[q];                   // tgt cols q*8 .. q*8+7
        const int kcs = q >> 2, qslot = q & 3;
        U.XF[(kcs * 2 + mt) * 64 + qslot * 16 + l16e]       = sa;
        U.XF[((kcs + 2) * 2 + mt) * 64 + qslot * 16 + l16e] = ta;
        if (q == 4) tgt_s[ee] = rt;
        if (q == 0) {        // edge features (cols 128..135) from bf16 chunk 0
            float dx = (float)sa[0] - (float)ta[0];
            float dy = (float)sa[1] - (float)ta[1];
            float dz = (float)sa[2] - (float)ta[2];
            float ax = (float)sa[3], ay = (float)sa[4], az = (float)sa[5];
            float bx = (float)ta[3], by = (float)ta[4], bz = (float)ta[5];
            float cx = ay * bz - az * by;
            float cy = az * bx - ax * bz;
            float cz = ax * by - ay * bx;
            bf16x8 f;
            f[0] = (__bf16)dx; f[1] = (__bf16)dy; f[2] = (__bf16)dz;
            f[3] = (__bf16)(dx * dx + dy * dy + dz * dz);
            f[4] = (__bf16)cx; f[5] = (__bf16)cy; f[6] = (__bf16)cz;
            f[7] = (__bf16)sqrtf(cx * cx + cy * cy + cz * cz);
            U.XF[(8 + mt) * 64 + l16e] = f;
        } else if (q >= 5) { // zero pad (cols 136..159)
            bf16x8 z;
#pragma unroll
            for (int i = 0; i < 8; i++) z[i] = (__bf16)0.f;
            U.XF[(8 + mt) * 64 + (q - 4) * 16 + l16e] = z;
        }
    }
    __syncthreads();                         // B1: XF + tgt_s ready

    // ---- GEMM1: wave owns 4 col-tiles (msg 2w,2w+1; gate 8+2w,8+2w+1) ----
    f32x4 acc[2][4];
#pragma unroll
    for (int nt = 0; nt < 4; nt++) {
        float b = (nt < 2) ? be1[(w * 2 + nt) * 16 + l16]
                           : bg1[(w * 2 + nt - 2) * 16 + l16];
#pragma unroll
        for (int mt = 0; mt < 2; mt++) { f32x4 v = {b, b, b, b}; acc[mt][nt] = v; }
    }
#pragma unroll
    for (int kc = 0; kc < 5; kc++) {
        bf16x8 bf0 = We1F[(kc * 16 + w * 2) * 64 + lane];
        bf16x8 bf1 = We1F[(kc * 16 + w * 2 + 1) * 64 + lane];
        bf16x8 bf2 = We1F[(kc * 16 + 8 + w * 2) * 64 + lane];
        bf16x8 bf3 = We1F[(kc * 16 + 8 + w * 2 + 1) * 64 + lane];
#pragma unroll
        for (int mt = 0; mt < 2; mt++) {
            bf16x8 af = U.XF[(kc * 2 + mt) * 64 + lane];
            acc[mt][0] = __builtin_amdgcn_mfma_f32_16x16x32_bf16(af, bf0, acc[mt][0], 0, 0, 0);
            acc[mt][1] = __builtin_amdgcn_mfma_f32_16x16x32_bf16(af, bf1, acc[mt][1], 0, 0, 0);
            acc[mt][2] = __builtin_amdgcn_mfma_f32_16x16x32_bf16(af, bf2, acc[mt][2], 0, 0, 0);
            acc[mt][3] = __builtin_amdgcn_mfma_f32_16x16x32_bf16(af, bf3, acc[mt][3], 0, 0, 0);
        }
    }
    __syncthreads();                         // B2: XF reads done (HF may overwrite)

    {   // ---- all waves: relu+transpose msg tiles -> HF, gate partials ----
        __bf16* HFp = (__bf16*)U.s.HF;
#pragma unroll
        for (int nt = 0; nt < 2; nt++) {
            int cw = (w * 2 + nt) * 16 + l16;
            int kc2 = cw >> 5, quad2 = (cw >> 3) & 3, ii = cw & 7;
#pragma unroll
            for (int mt = 0; mt < 2; mt++)
#pragma unroll
                for (int r = 0; r < 4; r++)
                    HFp[(((kc2 * 2 + mt) * 64) + quad2 * 16 + quad * 4 + r) * 8 + ii] =
                        (__bf16)fmaxf(acc[mt][nt][r], 0.f);
        }
        float gp[2][4];
#pragma unroll
        for (int mt = 0; mt < 2; mt++)
#pragma unroll
            for (int r = 0; r < 4; r++) gp[mt][r] = 0.f;
#pragma unroll
        for (int nt = 2; nt < 4; nt++) {
            float wg = Wg2[(w * 2 + nt - 2) * 16 + l16];
#pragma unroll
            for (int mt = 0; mt < 2; mt++)
#pragma unroll
                for (int r = 0; r < 4; r++)
                    gp[mt][r] += fmaxf(acc[mt][nt][r], 0.f) * wg;
        }
#pragma unroll
        for (int mask = 1; mask < 16; mask <<= 1)
#pragma unroll
            for (int mt = 0; mt < 2; mt++)
#pragma unroll
                for (int r = 0; r < 4; r++)
                    gp[mt][r] += __shfl_xor(gp[mt][r], mask, 64);
        if (l16 == 0) {
#pragma unroll
            for (int mt = 0; mt < 2; mt++)
#pragma unroll
                for (int r = 0; r < 4; r++)
                    gred[w][mt * 16 + quad * 4 + r] = gp[mt][r];
        }
    }
    __syncthreads();                         // B3: HF + gred ready

    {   // ---- GEMM2 (all 4 waves, col-tile w) + sigmoid + M pack ----
        f32x4 acc2[2];
        float b2 = be2[w * 16 + l16];
#pragma unroll
        for (int mt = 0; mt < 2; mt++) { f32x4 v = {b2, b2, b2, b2}; acc2[mt] = v; }
#pragma unroll
        for (int kc = 0; kc < 4; kc++) {
            bf16x8 c2 = We2F[(kc * 4 + w) * 64 + lane];
#pragma unroll
            for (int mt = 0; mt < 2; mt++)
                acc2[mt] = __builtin_amdgcn_mfma_f32_16x16x32_bf16(
                    U.s.HF[(kc * 2 + mt) * 64 + lane], c2, acc2[mt], 0, 0, 0);
        }

        // redundant per-lane sigmoid from gred (lanes 32-63 mirror 0-31)
        float wgtreg;
        {
            int e = lane & 31;
            float g = bg2[0] + gred[0][e] + gred[1][e] + gred[2][e] + gred[3][e];
            wgtreg = 1.f / (1.f + __expf(-g));
        }

#pragma unroll
        for (int mt = 0; mt < 2; mt++)
#pragma unroll
            for (int r = 0; r < 4; r++) {
                int edge = mt * 16 + quad * 4 + r;
                float wg = __shfl(wgtreg, edge, 64);
                U.s.M[edge * 68 + w * 16 + l16] =
                    (_Float16)(acc2[mt][r] * wg);
            }
    }
    __syncthreads();                         // B4: M ready

    // ---- scatter: all 4 waves, packed v2f16 atomics ----
    // thread t, step k: edge = (t>>5) + 8k, pair p = t&31.
    // per wave-instr: 2 rows x 128 B = 4 cachelines x 16 lanes.
    {
        const int p = t & 31, eh = t >> 5;
        char* base = (char*)magg_rows;
#pragma unroll
        for (int k = 0; k < 4; k++) {
            int e = eh + k * 8;
            f16x2 v = *(const f16x2*)&U.s.M[e * 68 + p * 2];
            pk_atomic_add_f16(base + (long)tgt_s[e] * 256 + p * 4, v);
        }
    }
}

// ---------------- node kernel: 512 thr, 2 barriers (separate XF/HF) --------
__global__ __launch_bounds__(512, 4) void node_kernel(
    const float* __restrict__ m_agg_w,
    const bf16x8* __restrict__ Wn1F, const bf16x8* __restrict__ Wn2F,
    const float* __restrict__ bn1, const float* __restrict__ bn2,
    float* __restrict__ outp)     // rows: f16 acc | bf16 z, then output
{
    __shared__ bf16x8 XF[1024];   // 16 KB
    __shared__ bf16x8 HF[1024];   // 16 KB (separate -> no XF/HF hazard barrier)
    const int t = threadIdx.x;
    const int n0 = blockIdx.x * 64;
    const int lane = t & 63, w = t >> 6;
    const int quad = lane >> 4, l16 = lane & 15;

    {   // gather: 8 threads/node; halves: z-bf16 | m_agg(f16) + m_agg_w
        int nn = t >> 3, q = t & 7;
        int mt = nn >> 4, l16e = nn & 15;
        int node = n0 + nn; if (node >= NN) node = NN - 1;
        int half = q >> 2, sub = q & 3;
        bf16x8 c0, c1;
        if (half == 0) {
            const bf16x8* zr = (const bf16x8*)((const char*)outp + (long)node * 256 + 128) + sub * 2;
            c0 = zr[0]; c1 = zr[1];
        } else {
            const f16x8* mr = (const f16x8*)((const char*)outp + (long)node * 256) + sub * 2;
            f16x8 r0 = mr[0], r1 = mr[1];
            const float* mw = m_agg_w + sub * 16;
#pragma unroll
            for (int i = 0; i < 8; i++) {
                c0[i] = (__bf16)((float)r0[i] + mw[i]);
                c1[i] = (__bf16)((float)r1[i] + mw[i + 8]);
            }
        }
        int kcs = (sub >> 1) + half * 2, qa = (sub & 1) * 2;
        XF[(kcs * 4 + mt) * 64 + qa * 16 + l16e]       = c0;
        XF[(kcs * 4 + mt) * 64 + (qa + 1) * 16 + l16e] = c1;
    }
    __syncthreads();                         // B1: XF ready

    f32x4 acc[4];
    {
        float b = bn1[w * 16 + l16];
#pragma unroll
        for (int mt = 0; mt < 4; mt++) { f32x4 v = {b, b, b, b}; acc[mt] = v; }
    }
#pragma unroll
    for (int kc = 0; kc < 4; kc++) {
        bf16x8 bfr = Wn1F[(kc * 8 + w) * 64 + lane];
#pragma unroll
        for (int mt = 0; mt < 4; mt++)
            acc[mt] = __builtin_amdgcn_mfma_f32_16x16x32_bf16(
                XF[(kc * 4 + mt) * 64 + lane], bfr, acc[mt], 0, 0, 0);
    }

    {   // relu + transpose -> HF (separate buffer: no barrier needed)
        __bf16* HFp = (__bf16*)HF;
        int cw = w * 16 + l16;
        int kc2 = cw >> 5, quad2 = (cw >> 3) & 3, ii = cw & 7;
#pragma unroll
        for (int mt = 0; mt < 4; mt++)
#pragma unroll
            for (int r = 0; r < 4; r++)
                HFp[(((kc2 * 4 + mt) * 64) + quad2 * 16 + quad * 4 + r) * 8 + ii] =
                    (__bf16)fmaxf(acc[mt][r], 0.f);
    }
    __syncthreads();                         // B2: HF ready

    {   // GEMM2 + store: nt = w&3, m-half mh = w>>2
        const int nt = w & 3, mh = w >> 2;
        f32x4 acc2[2];
        float b2 = bn2[nt * 16 + l16];
#pragma unroll
        for (int m = 0; m < 2; m++) { f32x4 v = {b2, b2, b2, b2}; acc2[m] = v; }
#pragma unroll
        for (int kc = 0; kc < 4; kc++) {
            bf16x8 b2f = Wn2F[(kc * 4 + nt) * 64 + lane];
#pragma unroll
            for (int m = 0; m < 2; m++)
                acc2[m] = __builtin_amdgcn_mfma_f32_16x16x32_bf16(
                    HF[(kc * 4 + mh * 2 + m) * 64 + lane], b2f, acc2[m], 0, 0, 0);
        }
#pragma unroll
        for (int m = 0; m < 2; m++)
#pragma unroll
            for (int r = 0; r < 4; r++) {
                int node = n0 + (mh * 2 + m) * 16 + quad * 4 + r;
                if (node < NN)
                    outp[(long)node * 64 + nt * 16 + l16] = acc2[m][r];
            }
    }
}

extern "C" void kernel_launch(void* const* d_in, const int* in_sizes, int n_in,
                              void* d_out, int out_size, void* d_ws, size_t ws_size,
                              hipStream_t stream)
{
    const float* z_h       = (const float*)d_in[0];
    const float* pos_world = (const float*)d_in[1];
    const int*   ei        = (const int*)d_in[2];
    const float* We1 = (const float*)d_in[3];  const float* be1 = (const float*)d_in[4];
    const float* We2 = (const float*)d_in[5];  const float* be2 = (const float*)d_in[6];
    const float* Wg1 = (const float*)d_in[7];  const float* bg1 = (const float*)d_in[8];
    const float* Wg2 = (const float*)d_in[9];  const float* bg2 = (const float*)d_in[10];
    const float* Wn1 = (const float*)d_in[11]; const float* bn1 = (const float*)d_in[12];
    const float* Wn2 = (const float*)d_in[13]; const float* bn2 = (const float*)d_in[14];
    const float* Ww1 = (const float*)d_in[15]; const float* bw1 = (const float*)d_in[16];
    const float* Ww2 = (const float*)d_in[17]; const float* bw2 = (const float*)d_in[18];

    float*  outp    = (float*)d_out;
    float*  m_agg_w = (float*)d_ws;         // 64 floats
    bf16x8* wsF     = (bf16x8*)((char*)d_ws + 256);

    prep<<<(NN * 8 + 255) / 256, 256, 0, stream>>>(
        We1, Wg1, We2, Wn1, Wn2, Ww1, Ww2, wsF, z_h, outp, m_agg_w);
    fused_kernel<<<EBLOCKS + WBLOCKS, 256, 0, stream>>>(
        z_h, ei, wsF + WE1F_OFF, wsF + WE2F_OFF,
        be1, be2, bg1, Wg2, bg2,
        pos_world, wsF + WW1F_OFF, wsF + WW2F_OFF, bw1, bw2,
        outp, m_agg_w);
    node_kernel<<<(NN + 63) / 64, 512, 0, stream>>>(
        m_agg_w, wsF + WN1F_OFF, wsF + WN2F_OFF, bn1, bn2, outp);
}